// Round 7
// baseline (1687.705 us; speedup 1.0000x reference)
//
#include <hip/hip_runtime.h>
#include <math.h>

// Problem constants (fixed by the reference).
#define N_NODES 50000
#define N_EDGES 640000   // divisible by 32 and 256; < 2^20 (index packs with combo)
#define NLAYER  4
#define NPAD    50016    // N_NODES rounded up to 32
#define NCOMBO  315      // 35 etypes x 9 rids

typedef unsigned short bf16_t;
typedef __attribute__((ext_vector_type(8))) short s16x8;   // 8 bf16 = 4 VGPR (MFMA A/B frag)
typedef __attribute__((ext_vector_type(4))) float f32x4;   // MFMA C/D frag

__device__ __forceinline__ float gelu_f(float x) {
    return 0.5f * x * (1.0f + tanhf(0.7978845608028654f * (x + 0.044715f * x * x * x)));
}

__device__ __forceinline__ bf16_t f2bf(float f) {
    unsigned u = __float_as_uint(f);
    unsigned r = (u + 0x7FFFu + ((u >> 16) & 1u)) >> 16;   // RNE
    return (bf16_t)r;
}
__device__ __forceinline__ float bf2f(bf16_t h) { return __uint_as_float(((unsigned)h) << 16); }
__device__ __forceinline__ float bfl(unsigned x) { return __uint_as_float(x << 16); }
__device__ __forceinline__ float bfh(unsigned x) { return __uint_as_float(x & 0xFFFF0000u); }

// ---------------- CSR build (counting sort by dst) ----------------
__global__ void k_zero32(unsigned* p, int n) {
    int i = blockIdx.x * 256 + threadIdx.x;
    if (i < n) p[i] = 0u;
}

__global__ void k_hist(const int* __restrict__ dst, int* __restrict__ deg) {
    int i = blockIdx.x * 256 + threadIdx.x;
    if (i < N_EDGES) atomicAdd(&deg[dst[i]], 1);
}

// combo histogram over ORIGINAL edge order (independent of the dst sort).
__global__ void k_chist(const int* __restrict__ etype, const int* __restrict__ erid,
                        int* __restrict__ ccnt) {
    int i = blockIdx.x * 256 + threadIdx.x;
    if (i < N_EDGES) atomicAdd(&ccnt[etype[i] * 9 + erid[i]], 1);
}

__global__ void k_cscan(const int* __restrict__ ccnt, int* __restrict__ ccur) {
    if (threadIdx.x == 0 && blockIdx.x == 0) {
        int run = 0;
        for (int c = 0; c < NCOMBO; c++) { ccur[c] = run; run += ccnt[c]; }
    }
}

__global__ void k_scan1(const int* __restrict__ deg, int* __restrict__ rowptr, int* __restrict__ bsum) {
    __shared__ int sd[1024];
    int gi = blockIdx.x * 1024 + threadIdx.x;
    int v = (gi < N_NODES) ? deg[gi] : 0;
    sd[threadIdx.x] = v;
    __syncthreads();
    for (int off = 1; off < 1024; off <<= 1) {
        int t2 = (threadIdx.x >= (unsigned)off) ? sd[threadIdx.x - off] : 0;
        __syncthreads();
        sd[threadIdx.x] += t2;
        __syncthreads();
    }
    if (gi < N_NODES) rowptr[gi] = sd[threadIdx.x] - v;  // block-local exclusive
    if (threadIdx.x == 1023) bsum[blockIdx.x] = sd[1023];
}

__global__ void k_scan2(const int* __restrict__ bsum, int* __restrict__ boff, int nb) {
    if (threadIdx.x == 0 && blockIdx.x == 0) {
        int run = 0;
        for (int b = 0; b < nb; b++) { boff[b] = run; run += bsum[b]; }
    }
}

// scan3 also seeds the scatter cursor (folds the old k_copy).
__global__ void k_scan3(int* __restrict__ rowptr, const int* __restrict__ boff,
                        int* __restrict__ cursor) {
    int gi = blockIdx.x * 1024 + threadIdx.x;
    if (gi < N_NODES) {
        int v = rowptr[gi] + boff[blockIdx.x];
        rowptr[gi] = v;
        cursor[gi] = v;
    }
    if (gi == 0) rowptr[N_NODES] = N_EDGES;
}

__global__ void k_scatter(const int* __restrict__ dst, int* __restrict__ cursor, int* __restrict__ eidx) {
    int i = blockIdx.x * 256 + threadIdx.x;
    if (i < N_EDGES) {
        int p = atomicAdd(&cursor[dst[i]], 1);
        eidx[p] = i;
    }
}

// Gather per-edge fields; emit COMBO-SORTED meta (24 B/edge) for k_edge and the
// dst-sorted src index for k_soft_agg.
// emC[p]  = { src, dst, combo<<20 | i_dstsorted, rc0|rc1<<16 (bf16) }
// emC2[p] = { rp0|rp1<<16 (bf16), rp2 (bf16) }
__global__ void k_sortgather(
    const int* __restrict__ eidx, const int* __restrict__ src, const int* __restrict__ dst,
    const int* __restrict__ etype, const int* __restrict__ erid,
    const float* __restrict__ att_rc, const float* __restrict__ att_rp,
    int* __restrict__ src_s, int* __restrict__ ccur,
    uint4* __restrict__ emC, uint2* __restrict__ emC2)
{
    int i = blockIdx.x * 256 + threadIdx.x;
    if (i < N_EDGES) {
        int e = eidx[i];
        int sv = src[e];
        src_s[i] = sv;
        int combo = etype[e] * 9 + erid[e];
        int p = atomicAdd(&ccur[combo], 1);
        uint4 a;
        a.x = (unsigned)sv;
        a.y = (unsigned)dst[e];
        a.z = ((unsigned)combo << 20) | (unsigned)i;
        a.w = (unsigned)f2bf(att_rc[2 * e]) | ((unsigned)f2bf(att_rc[2 * e + 1]) << 16);
        uint2 b;
        b.x = (unsigned)f2bf(att_rp[3 * e]) | ((unsigned)f2bf(att_rp[3 * e + 1]) << 16);
        b.y = (unsigned)f2bf(att_rp[3 * e + 2]);
        emC[p] = a;
        emC2[p] = b;
    }
}

// ---------------- (etype,erid)-combo base table: 315 x 64 fp32 ----------
__global__ void k_base(const float* __restrict__ type_emb, const float* __restrict__ rid_emb,
                       const float* __restrict__ rcb, const float* __restrict__ rpb,
                       float* __restrict__ base)
{
    int idx = blockIdx.x * 256 + threadIdx.x;
    if (idx >= NCOMBO * 64) return;
    int c = idx >> 6, k = idx & 63;
    int et = c / 9, er = c % 9;
    base[idx] = type_emb[et * 64 + k] + rid_emb[er * 64 + k] + rcb[k] + rpb[k];
}

// ---------------- rank-factorized edge projection tables (per layer, fp32) ----------
// baseW[l][c][n] = sum_k base[c][k] * Wfij[l][k][n]
__global__ void k_basew(const float* __restrict__ base, const float* __restrict__ Wfij,
                        float* __restrict__ baseW)
{
    int idx = blockIdx.x * 256 + threadIdx.x;
    if (idx >= NLAYER * NCOMBO * 128) return;
    int l = idx / (NCOMBO * 128), r = idx % (NCOMBO * 128);
    int c = r >> 7, n = r & 127;
    const float* bp = base + c * 64;
    const float* wp = Wfij + l * 8192 + n;
    float acc = 0.f;
#pragma unroll 8
    for (int k = 0; k < 64; k++) acc = fmaf(bp[k], wp[k * 128], acc);
    baseW[idx] = acc;
}

// CWf[l][j][n] = sum_k w_j[k] * Wfij[l][k][n]
__global__ void k_cw(const float* __restrict__ rcW, const float* __restrict__ rpW,
                     const float* __restrict__ Wfij, float* __restrict__ CWf)
{
    int idx = blockIdx.x * 256 + threadIdx.x;
    if (idx >= NLAYER * 5 * 128) return;
    int l = idx / 640, r = idx % 640;
    int j = r >> 7, n = r & 127;
    const float* cp = (j < 2) ? (rcW + j * 64) : (rpW + (j - 2) * 64);
    const float* wp = Wfij + l * 8192 + n;
    float acc = 0.f;
#pragma unroll 8
    for (int k = 0; k < 64; k++) acc = fmaf(cp[k], wp[k * 128], acc);
    CWf[idx] = acc;
}

// Weight transposes to bf16, k-contiguous rows (MFMA A-operand friendly).
__global__ void k_wprep(const float* __restrict__ Wfij, const float* __restrict__ Wni,
                        const float* __restrict__ Wnj, const float* __restrict__ Wnode,
                        const float* __restrict__ W1, const float* __restrict__ W2,
                        bf16_t* __restrict__ WT, bf16_t* __restrict__ W3T,
                        bf16_t* __restrict__ W1T, bf16_t* __restrict__ W2T)
{
    int idx = blockIdx.x * 256 + threadIdx.x;
    if (idx >= NLAYER * 57344) return;
    int l = idx / 57344, r = idx % 57344;
    if (r < 8192) {
        int n = r >> 6, k = r & 63;
        WT[l * 8192 + r] = f2bf(Wfij[l * 8192 + k * 128 + n]);
    } else if (r < 32768) {
        int q = r - 8192; int c = q >> 6, k = q & 63;
        const float* src = (c < 128) ? Wni : (c < 256) ? Wnj : Wnode;
        W3T[l * 24576 + q] = f2bf(src[l * 8192 + k * 128 + (c & 127)]);
    } else if (r < 49152) {
        int q = r - 32768; int n = q >> 7, k = q & 127;
        W1T[l * 16384 + q] = f2bf(W1[l * 16384 + k * 128 + n]);
    } else {
        int q = r - 49152; int j = q >> 7, k = q & 127;
        W2T[l * 8192 + q] = f2bf(W2[l * 8192 + k * 64 + j]);
    }
}

// ---------------- feature encoder: h0 = gelu(feat@W1+b1)@W2+b2 ----------------
__global__ __launch_bounds__(256) void k_fe(
    const float* __restrict__ feat, const float* __restrict__ W1, const float* __restrict__ b1,
    const float* __restrict__ W2, const float* __restrict__ b2,
    float* __restrict__ h, bf16_t* __restrict__ hb, float* __restrict__ out)
{
    __shared__ float hid[4][64];
    int w = threadIdx.x >> 6, lane = threadIdx.x & 63;
    int n = blockIdx.x * 4 + w;  // N divisible by 4
    float a = b1[lane];
#pragma unroll 8
    for (int k = 0; k < 32; k++) a = fmaf(feat[n * 32 + k], W1[k * 64 + lane], a);
    hid[w][lane] = gelu_f(a);
    __syncthreads();
    float o = b2[lane];
#pragma unroll 8
    for (int k = 0; k < 64; k++) o = fmaf(hid[w][k], W2[k * 64 + lane], o);
    h[n * 64 + lane] = o;
    hb[n * 64 + lane] = f2bf(o);
    out[n * 704 + 32 + lane] = o;
    if (lane < 32) out[n * 704 + lane] = feat[n * 32 + lane];
}

// ---------------- s = h @ [W_ni | W_nj | W_node(+b)] -> [NPAD,384] bf16, MFMA ----------------
__global__ __launch_bounds__(256) void k_node3(
    const bf16_t* __restrict__ hb, const bf16_t* __restrict__ W3T,
    const float* __restrict__ bnode, bf16_t* __restrict__ s)
{
    __shared__ __align__(16) bf16_t hbS[32 * 72];
    const int t = threadIdx.x;
    const int wave = t >> 6, lane = t & 63, l16 = lane & 15, quad = lane >> 4;
    const int n0 = blockIdx.x * 32;
    {   // stage hb tile: 32 rows x 128B
        int r = t >> 3, sg = t & 7;
        *(s16x8*)(hbS + r * 72 + sg * 8) = *(const s16x8*)(hb + (size_t)(n0 + r) * 64 + sg * 8);
    }
    __syncthreads();
    const int ng = wave & 1, ch = wave >> 1;
    const s16x8 B0 = *(const s16x8*)(hbS + (ng * 16 + l16) * 72 + quad * 8);
    const s16x8 B1 = *(const s16x8*)(hbS + (ng * 16 + l16) * 72 + 32 + quad * 8);
    const int node = n0 + ng * 16 + l16;
#pragma unroll
    for (int nt = 0; nt < 12; nt++) {
        int c0 = ch * 192 + nt * 16;
        const s16x8 A0 = *(const s16x8*)(W3T + (size_t)(c0 + l16) * 64 + quad * 8);
        const s16x8 A1 = *(const s16x8*)(W3T + (size_t)(c0 + l16) * 64 + 32 + quad * 8);
        f32x4 acc = {0.f, 0.f, 0.f, 0.f};
        acc = __builtin_amdgcn_mfma_f32_16x16x32_bf16(A0, B0, acc, 0, 0, 0);
        acc = __builtin_amdgcn_mfma_f32_16x16x32_bf16(A1, B1, acc, 0, 0, 0);
        int cb = c0 + quad * 4;
        float4 bv = make_float4(0.f, 0.f, 0.f, 0.f);
        if (cb >= 256) bv = *(const float4*)(bnode + cb - 256);
        ushort4 o;
        o.x = f2bf(acc[0] + bv.x);
        o.y = f2bf(acc[1] + bv.y);
        o.z = f2bf(acc[2] + bv.z);
        o.w = f2bf(acc[3] + bv.w);
        *(ushort4*)(s + (size_t)node * 384 + cb) = o;
    }
}

// ---------------- fused edge kernel: combo-sorted, 2 edges/thread, pure VALU ----------------
// Edges processed in combo-sorted order -> all lanes share (nearly always) one combo, so the
// baseW row loads are same-address wave broadcasts (L1-hit) instead of 64-line gathers.
// CWf/attn loads are address-uniform; each table load now feeds TWO edges' fma chains (ILP).
// Math identical to the harness-verified R6 kernel (same op order per edge); only the edge
// processing order changed. Results written to evals[i_dstsorted] (packed in meta).
__global__ __launch_bounds__(256) void k_edge(
    const bf16_t* __restrict__ s, const float* __restrict__ baseW,
    const float* __restrict__ CWf, const float* __restrict__ attn,
    const uint4* __restrict__ emC, const uint2* __restrict__ emC2,
    float* __restrict__ evals)
{
    const int t = blockIdx.x * 256 + threadIdx.x;   // grid covers N_EDGES/2 exactly
    const int j = 2 * t;
    const uint4 mA = emC[j], mB = emC[j + 1];
    const uint2 nA = emC2[j], nB = emC2[j + 1];
    const bf16_t* srA = s + (size_t)mA.x * 384;          // sni dims 0..63
    const bf16_t* drA = s + (size_t)mA.y * 384 + 128;    // snj dims 0..63
    const bf16_t* srB = s + (size_t)mB.x * 384;
    const bf16_t* drB = s + (size_t)mB.y * 384 + 128;
    const float* bwA = baseW + (size_t)(mA.z >> 20) * 128;
    const float* bwB = baseW + (size_t)(mB.z >> 20) * 128;
    const float rA0 = bfl(mA.w), rA1 = bfh(mA.w);
    const float rA2 = bfl(nA.x), rA3 = bfh(nA.x), rA4 = bfl(nA.y);
    const float rB0 = bfl(mB.w), rB1 = bfh(mB.w);
    const float rB2 = bfl(nB.x), rB3 = bfh(nB.x), rB4 = bfl(nB.y);

    float eA[2] = {0.f, 0.f};
    float eB[2] = {0.f, 0.f};
#pragma unroll
    for (int c = 0; c < 4; c++) {
        const int d0 = c * 16;
        const uint4 uA0 = *(const uint4*)(srA + d0);
        const uint4 uA1 = *(const uint4*)(srA + d0 + 8);
        const uint4 vA0 = *(const uint4*)(drA + d0);
        const uint4 vA1 = *(const uint4*)(drA + d0 + 8);
        const uint4 uB0 = *(const uint4*)(srB + d0);
        const uint4 uB1 = *(const uint4*)(srB + d0 + 8);
        const uint4 vB0 = *(const uint4*)(drB + d0);
        const uint4 vB1 = *(const uint4*)(drB + d0 + 8);
        float sndA[16], sndB[16];
        sndA[0]  = bfl(uA0.x) + bfl(vA0.x);  sndA[1]  = bfh(uA0.x) + bfh(vA0.x);
        sndA[2]  = bfl(uA0.y) + bfl(vA0.y);  sndA[3]  = bfh(uA0.y) + bfh(vA0.y);
        sndA[4]  = bfl(uA0.z) + bfl(vA0.z);  sndA[5]  = bfh(uA0.z) + bfh(vA0.z);
        sndA[6]  = bfl(uA0.w) + bfl(vA0.w);  sndA[7]  = bfh(uA0.w) + bfh(vA0.w);
        sndA[8]  = bfl(uA1.x) + bfl(vA1.x);  sndA[9]  = bfh(uA1.x) + bfh(vA1.x);
        sndA[10] = bfl(uA1.y) + bfl(vA1.y);  sndA[11] = bfh(uA1.y) + bfh(vA1.y);
        sndA[12] = bfl(uA1.z) + bfl(vA1.z);  sndA[13] = bfh(uA1.z) + bfh(vA1.z);
        sndA[14] = bfl(uA1.w) + bfl(vA1.w);  sndA[15] = bfh(uA1.w) + bfh(vA1.w);
        sndB[0]  = bfl(uB0.x) + bfl(vB0.x);  sndB[1]  = bfh(uB0.x) + bfh(vB0.x);
        sndB[2]  = bfl(uB0.y) + bfl(vB0.y);  sndB[3]  = bfh(uB0.y) + bfh(vB0.y);
        sndB[4]  = bfl(uB0.z) + bfl(vB0.z);  sndB[5]  = bfh(uB0.z) + bfh(vB0.z);
        sndB[6]  = bfl(uB0.w) + bfl(vB0.w);  sndB[7]  = bfh(uB0.w) + bfh(vB0.w);
        sndB[8]  = bfl(uB1.x) + bfl(vB1.x);  sndB[9]  = bfh(uB1.x) + bfh(vB1.x);
        sndB[10] = bfl(uB1.y) + bfl(vB1.y);  sndB[11] = bfh(uB1.y) + bfh(vB1.y);
        sndB[12] = bfl(uB1.z) + bfl(vB1.z);  sndB[13] = bfh(uB1.z) + bfh(vB1.z);
        sndB[14] = bfl(uB1.w) + bfl(vB1.w);  sndB[15] = bfh(uB1.w) + bfh(vB1.w);
#pragma unroll
        for (int h = 0; h < 2; h++) {
#pragma unroll
            for (int q = 0; q < 4; q++) {
                const int n = h * 64 + d0 + q * 4;
                const float4 w0 = *(const float4*)(CWf + n);
                const float4 w1 = *(const float4*)(CWf + 128 + n);
                const float4 w2 = *(const float4*)(CWf + 256 + n);
                const float4 w3 = *(const float4*)(CWf + 384 + n);
                const float4 w4 = *(const float4*)(CWf + 512 + n);
                const float4 at = *(const float4*)(attn + n);
                const float4 bA = *(const float4*)(bwA + n);
                const float4 bB = *(const float4*)(bwB + n);
                float f0 = bA.x, f1 = bA.y, f2 = bA.z, f3 = bA.w;
                f0 = fmaf(rA0, w0.x, f0); f1 = fmaf(rA0, w0.y, f1); f2 = fmaf(rA0, w0.z, f2); f3 = fmaf(rA0, w0.w, f3);
                f0 = fmaf(rA1, w1.x, f0); f1 = fmaf(rA1, w1.y, f1); f2 = fmaf(rA1, w1.z, f2); f3 = fmaf(rA1, w1.w, f3);
                f0 = fmaf(rA2, w2.x, f0); f1 = fmaf(rA2, w2.y, f1); f2 = fmaf(rA2, w2.z, f2); f3 = fmaf(rA2, w2.w, f3);
                f0 = fmaf(rA3, w3.x, f0); f1 = fmaf(rA3, w3.y, f1); f2 = fmaf(rA3, w3.z, f2); f3 = fmaf(rA3, w3.w, f3);
                f0 = fmaf(rA4, w4.x, f0); f1 = fmaf(rA4, w4.y, f1); f2 = fmaf(rA4, w4.z, f2); f3 = fmaf(rA4, w4.w, f3);
                f0 += sndA[q * 4 + 0];
                f1 += sndA[q * 4 + 1];
                f2 += sndA[q * 4 + 2];
                f3 += sndA[q * 4 + 3];
                f0 = (f0 >= 0.f) ? f0 : 0.2f * f0;
                f1 = (f1 >= 0.f) ? f1 : 0.2f * f1;
                f2 = (f2 >= 0.f) ? f2 : 0.2f * f2;
                f3 = (f3 >= 0.f) ? f3 : 0.2f * f3;
                eA[h] = fmaf(f0, at.x, eA[h]);
                eA[h] = fmaf(f1, at.y, eA[h]);
                eA[h] = fmaf(f2, at.z, eA[h]);
                eA[h] = fmaf(f3, at.w, eA[h]);
                float g0 = bB.x, g1 = bB.y, g2 = bB.z, g3 = bB.w;
                g0 = fmaf(rB0, w0.x, g0); g1 = fmaf(rB0, w0.y, g1); g2 = fmaf(rB0, w0.z, g2); g3 = fmaf(rB0, w0.w, g3);
                g0 = fmaf(rB1, w1.x, g0); g1 = fmaf(rB1, w1.y, g1); g2 = fmaf(rB1, w1.z, g2); g3 = fmaf(rB1, w1.w, g3);
                g0 = fmaf(rB2, w2.x, g0); g1 = fmaf(rB2, w2.y, g1); g2 = fmaf(rB2, w2.z, g2); g3 = fmaf(rB2, w2.w, g3);
                g0 = fmaf(rB3, w3.x, g0); g1 = fmaf(rB3, w3.y, g1); g2 = fmaf(rB3, w3.z, g2); g3 = fmaf(rB3, w3.w, g3);
                g0 = fmaf(rB4, w4.x, g0); g1 = fmaf(rB4, w4.y, g1); g2 = fmaf(rB4, w4.z, g2); g3 = fmaf(rB4, w4.w, g3);
                g0 += sndB[q * 4 + 0];
                g1 += sndB[q * 4 + 1];
                g2 += sndB[q * 4 + 2];
                g3 += sndB[q * 4 + 3];
                g0 = (g0 >= 0.f) ? g0 : 0.2f * g0;
                g1 = (g1 >= 0.f) ? g1 : 0.2f * g1;
                g2 = (g2 >= 0.f) ? g2 : 0.2f * g2;
                g3 = (g3 >= 0.f) ? g3 : 0.2f * g3;
                eB[h] = fmaf(g0, at.x, eB[h]);
                eB[h] = fmaf(g1, at.y, eB[h]);
                eB[h] = fmaf(g2, at.z, eB[h]);
                eB[h] = fmaf(g3, at.w, eB[h]);
            }
        }
    }
    float2 oA; oA.x = eA[0]; oA.y = eA[1];
    float2 oB; oB.x = eB[0]; oB.y = eB[1];
    *(float2*)(evals + 2 * (size_t)(mA.z & 0xFFFFFu)) = oA;
    *(float2*)(evals + 2 * (size_t)(mB.z & 0xFFFFFu)) = oB;
}

// ---------------- per-dst softmax + aggregation -> aggb bf16 ----------------
__global__ __launch_bounds__(256) void k_soft_agg(
    const int* __restrict__ rowptr, const int* __restrict__ src_s,
    const float* __restrict__ evals, const bf16_t* __restrict__ s,
    unsigned* __restrict__ aggb)   // [NPAD][64] uints = [NPAD][128] bf16
{
    int lane = threadIdx.x & 63;
    int wid = (blockIdx.x * 256 + threadIdx.x) >> 6;
    int nw = (gridDim.x * 256) >> 6;
    const int hb = (lane >> 4) & 1;                    // head for this lane's dims
    const int esel = lane >> 5;                        // 0: even edge of pair, 1: odd
    const int s32 = (lane & 15) | ((lane >> 5) << 4);  // 0..31 within head-group
    const int dsel = (lane & 31) * 4;                  // 4 bf16 dims per lane
    for (int n = wid; n < N_NODES; n += nw) {
        int r0 = rowptr[n], r1 = rowptr[n + 1];
        if (r0 == r1) {
            if (lane < 32) { uint2 z; z.x = 0u; z.y = 0u; *(uint2*)(aggb + (size_t)n * 64 + lane * 2) = z; }
            continue;
        }
        float mm = -1e30f;
        for (int i = r0 + s32; i < r1; i += 32) mm = fmaxf(mm, evals[2 * i + hb]);
        mm = fmaxf(mm, __shfl_xor(mm, 1));
        mm = fmaxf(mm, __shfl_xor(mm, 2));
        mm = fmaxf(mm, __shfl_xor(mm, 4));
        mm = fmaxf(mm, __shfl_xor(mm, 8));
        mm = fmaxf(mm, __shfl_xor(mm, 32));
        float z = 0.f;
        for (int i = r0 + s32; i < r1; i += 32) z += expf(evals[2 * i + hb] - mm);
        z += __shfl_xor(z, 1);
        z += __shfl_xor(z, 2);
        z += __shfl_xor(z, 4);
        z += __shfl_xor(z, 8);
        z += __shfl_xor(z, 32);
        float rz = 1.f / z;
        float acc0 = 0.f, acc1 = 0.f, acc2 = 0.f, acc3 = 0.f;
        for (int i = r0; i < r1; i += 8) {
            uint2 cc[4]; float ww[4];
#pragma unroll
            for (int p = 0; p < 4; p++) {
                int ej = i + 2 * p + esel;
                bool v = ej < r1;
                int es = v ? ej : r0;
                cc[p] = *(const uint2*)(s + (size_t)src_s[es] * 384 + 256 + dsel);
                ww[p] = v ? expf(evals[2 * ej + hb] - mm) * rz : 0.f;
            }
#pragma unroll
            for (int p = 0; p < 4; p++) {
                acc0 = fmaf(ww[p], bfl(cc[p].x), acc0);
                acc1 = fmaf(ww[p], bfh(cc[p].x), acc1);
                acc2 = fmaf(ww[p], bfl(cc[p].y), acc2);
                acc3 = fmaf(ww[p], bfh(cc[p].y), acc3);
            }
        }
        acc0 += __shfl_xor(acc0, 32);
        acc1 += __shfl_xor(acc1, 32);
        acc2 += __shfl_xor(acc2, 32);
        acc3 += __shfl_xor(acc3, 32);
        if (lane < 32) {
            uint2 o;
            o.x = (unsigned)f2bf(acc0) | ((unsigned)f2bf(acc1) << 16);
            o.y = (unsigned)f2bf(acc2) | ((unsigned)f2bf(acc3) << 16);
            *(uint2*)(aggb + (size_t)n * 64 + lane * 2) = o;
        }
    }
}

// ---------------- node MLP + residual, MFMA: h' = gelu(agg@W1+b1)@W2+b2 + h ----------------
__global__ __launch_bounds__(256) void k_mlp(
    const bf16_t* __restrict__ aggb, const bf16_t* __restrict__ W1T, const float* __restrict__ b1,
    const bf16_t* __restrict__ W2T, const float* __restrict__ b2,
    const float* __restrict__ hin, float* __restrict__ hout, bf16_t* __restrict__ houtb,
    float* __restrict__ out, int col0)
{
    __shared__ __align__(16) bf16_t aggS[32 * 136];
    __shared__ __align__(16) bf16_t hidS[32 * 136];
    const int t = threadIdx.x;
    const int wave = t >> 6, lane = t & 63, l16 = lane & 15, quad = lane >> 4;
    const int n0 = blockIdx.x * 32;
    {   // stage agg tile: 32 rows x 256B (32B per thread)
        int r = t >> 3, sg = t & 7;
        *(s16x8*)(aggS + r * 136 + sg * 16) =
            *(const s16x8*)(aggb + (size_t)(n0 + r) * 128 + sg * 16);
        *(s16x8*)(aggS + r * 136 + sg * 16 + 8) =
            *(const s16x8*)(aggb + (size_t)(n0 + r) * 128 + sg * 16 + 8);
    }
    __syncthreads();
    const int ng = wave & 1, nh = wave >> 1;
    const int node = n0 + ng * 16 + l16;
    {   // GEMM1 + gelu -> hidS
        const bf16_t* brow = aggS + (ng * 16 + l16) * 136 + quad * 8;
        s16x8 B[4];
#pragma unroll
        for (int ks = 0; ks < 4; ks++) B[ks] = *(const s16x8*)(brow + ks * 32);
#pragma unroll
        for (int nt = 0; nt < 4; nt++) {
            int nb = nh * 64 + nt * 16;
            f32x4 acc = {0.f, 0.f, 0.f, 0.f};
#pragma unroll
            for (int ks = 0; ks < 4; ks++) {
                const s16x8 A = *(const s16x8*)(W1T + (size_t)(nb + l16) * 128 + ks * 32 + quad * 8);
                acc = __builtin_amdgcn_mfma_f32_16x16x32_bf16(A, B[ks], acc, 0, 0, 0);
            }
            const float4 bv = *(const float4*)(b1 + nb + quad * 4);
            ushort4 o;
            o.x = f2bf(gelu_f(acc[0] + bv.x));
            o.y = f2bf(gelu_f(acc[1] + bv.y));
            o.z = f2bf(gelu_f(acc[2] + bv.z));
            o.w = f2bf(gelu_f(acc[3] + bv.w));
            *(ushort4*)(hidS + (ng * 16 + l16) * 136 + nb + quad * 4) = o;
        }
    }
    __syncthreads();
    {   // GEMM2 + bias + residual -> hout/houtb/out
        const int jh = wave >> 1;
        const bf16_t* hrow = hidS + (ng * 16 + l16) * 136 + quad * 8;
        s16x8 H[4];
#pragma unroll
        for (int ks = 0; ks < 4; ks++) H[ks] = *(const s16x8*)(hrow + ks * 32);
#pragma unroll
        for (int jt = 0; jt < 2; jt++) {
            int jb = jh * 32 + jt * 16;
            f32x4 acc = {0.f, 0.f, 0.f, 0.f};
#pragma unroll
            for (int ks = 0; ks < 4; ks++) {
                const s16x8 A = *(const s16x8*)(W2T + (size_t)(jb + l16) * 128 + ks * 32 + quad * 8);
                acc = __builtin_amdgcn_mfma_f32_16x16x32_bf16(A, H[ks], acc, 0, 0, 0);
            }
            int j0 = jb + quad * 4;
            const float4 bv = *(const float4*)(b2 + j0);
            const float4 hv = *(const float4*)(hin + (size_t)node * 64 + j0);
            float4 v;
            v.x = acc[0] + bv.x + hv.x;
            v.y = acc[1] + bv.y + hv.y;
            v.z = acc[2] + bv.z + hv.z;
            v.w = acc[3] + bv.w + hv.w;
            *(float4*)(hout + (size_t)node * 64 + j0) = v;
            ushort4 ob;
            ob.x = f2bf(v.x); ob.y = f2bf(v.y); ob.z = f2bf(v.z); ob.w = f2bf(v.w);
            *(ushort4*)(houtb + (size_t)node * 64 + j0) = ob;
            if (node < N_NODES)
                *(float4*)(out + (size_t)node * 704 + col0 + j0) = v;
        }
    }
}

// ---------------- graph max pooling over node_emb cols 0..351 ----------------
__device__ __forceinline__ unsigned fmap(float v) {
    unsigned u = __float_as_uint(v);
    return (u & 0x80000000u) ? ~u : (u | 0x80000000u);
}

__global__ __launch_bounds__(384) void k_colmax(const float* __restrict__ out, unsigned* __restrict__ gmax) {
    int c = threadIdx.x;
    if (c >= 352) return;
    float m = -1e30f;
    for (int n = blockIdx.x; n < N_NODES; n += gridDim.x)
        m = fmaxf(m, out[(size_t)n * 704 + c]);
    atomicMax(gmax + c, fmap(m));
}

__global__ __launch_bounds__(384) void k_bcast(const unsigned* __restrict__ gmax, float* __restrict__ out) {
    int c = threadIdx.x;
    if (c >= 352) return;
    unsigned u = gmax[c];
    u = (u & 0x80000000u) ? (u ^ 0x80000000u) : ~u;
    float v = __uint_as_float(u);
    for (int n = blockIdx.x; n < N_NODES; n += gridDim.x)
        out[(size_t)n * 704 + 352 + c] = v;
}

// ---------------- host launcher ----------------
extern "C" void kernel_launch(void* const* d_in, const int* in_sizes, int n_in,
                              void* d_out, int out_size, void* d_ws, size_t ws_size,
                              hipStream_t stream)
{
    (void)in_sizes; (void)n_in; (void)out_size; (void)ws_size;
    const float* feat     = (const float*)d_in[0];
    const float* att_rc   = (const float*)d_in[1];
    const float* att_rp   = (const float*)d_in[2];
    const float* type_emb = (const float*)d_in[3];
    const float* rid_emb  = (const float*)d_in[4];
    const float* rc_W     = (const float*)d_in[5];
    const float* rc_b     = (const float*)d_in[6];
    const float* rp_W     = (const float*)d_in[7];
    const float* rp_b     = (const float*)d_in[8];
    const float* fe_W1    = (const float*)d_in[9];
    const float* fe_b1    = (const float*)d_in[10];
    const float* fe_W2    = (const float*)d_in[11];
    const float* fe_b2    = (const float*)d_in[12];
    const float* W_ni     = (const float*)d_in[13];
    const float* W_nj     = (const float*)d_in[14];
    const float* W_fij    = (const float*)d_in[15];
    const float* W_node   = (const float*)d_in[16];
    const float* b_node   = (const float*)d_in[17];
    const float* attn     = (const float*)d_in[18];
    const float* mlp_W1   = (const float*)d_in[19];
    const float* mlp_b1   = (const float*)d_in[20];
    const float* mlp_W2   = (const float*)d_in[21];
    const float* mlp_b2   = (const float*)d_in[22];
    const int* src   = (const int*)d_in[23];
    const int* dst   = (const int*)d_in[24];
    const int* etype = (const int*)d_in[25];
    const int* erid  = (const int*)d_in[26];
    float* out = (float*)d_out;

    // Workspace layout (byte cursor, all chunks 16B aligned).
    char* cur = (char*)d_ws;
    auto alloc = [&](size_t bytes) { char* p = cur; cur += (bytes + 15) & ~(size_t)15; return p; };
    float* h_a    = (float*)alloc((size_t)NPAD * 64 * 4);
    float* h_b    = (float*)alloc((size_t)NPAD * 64 * 4);
    bf16_t* hb_a  = (bf16_t*)alloc((size_t)NPAD * 64 * 2);
    bf16_t* hb_b  = (bf16_t*)alloc((size_t)NPAD * 64 * 2);
    bf16_t* s     = (bf16_t*)alloc((size_t)NPAD * 384 * 2);
    float* ev     = (float*)alloc((size_t)N_EDGES * 2 * 4);
    bf16_t* aggb  = (bf16_t*)alloc((size_t)NPAD * 128 * 2);
    int* deg     = (int*)alloc((size_t)N_NODES * 4);
    int* rowptr  = (int*)alloc((size_t)(N_NODES + 1) * 4);
    int* cursor  = (int*)alloc((size_t)N_NODES * 4);
    int* eidx    = (int*)alloc((size_t)N_EDGES * 4);
    int* src_s   = (int*)alloc((size_t)N_EDGES * 4);
    uint4* emC   = (uint4*)alloc((size_t)N_EDGES * 16);
    uint2* emC2  = (uint2*)alloc((size_t)N_EDGES * 8);
    float* baseT = (float*)alloc((size_t)NCOMBO * 64 * 4);
    float* baseW = (float*)alloc((size_t)NLAYER * NCOMBO * 128 * 4);
    float* CWf   = (float*)alloc((size_t)NLAYER * 5 * 128 * 4);
    bf16_t* WT   = (bf16_t*)alloc((size_t)NLAYER * 128 * 64 * 2);
    bf16_t* W3T  = (bf16_t*)alloc((size_t)NLAYER * 384 * 64 * 2);
    bf16_t* W1T  = (bf16_t*)alloc((size_t)NLAYER * 128 * 128 * 2);
    bf16_t* W2T  = (bf16_t*)alloc((size_t)NLAYER * 64 * 128 * 2);
    int* bsum    = (int*)alloc(64 * 4);
    int* boff    = (int*)alloc(64 * 4);
    unsigned* gmax = (unsigned*)alloc(352 * 4);   // gmax(352) + ccnt(315) must stay contiguous
    int* ccnt    = (int*)alloc((size_t)NCOMBO * 4);
    int* ccur    = (int*)alloc((size_t)NCOMBO * 4);

    const int NB = (N_NODES + 1023) / 1024;  // 49

    k_zero32<<<(N_NODES + 255) / 256, 256, 0, stream>>>((unsigned*)deg, N_NODES);
    k_zero32<<<3, 256, 0, stream>>>(gmax, 352 + NCOMBO);   // zero gmax + ccnt (contiguous: 352*4 is 16B-aligned)
    k_hist<<<N_EDGES / 256, 256, 0, stream>>>(dst, deg);
    k_chist<<<N_EDGES / 256, 256, 0, stream>>>(etype, erid, ccnt);
    k_scan1<<<NB, 1024, 0, stream>>>(deg, rowptr, bsum);
    k_scan2<<<1, 64, 0, stream>>>(bsum, boff, NB);
    k_scan3<<<NB, 1024, 0, stream>>>(rowptr, boff, cursor);
    k_scatter<<<N_EDGES / 256, 256, 0, stream>>>(dst, cursor, eidx);
    k_cscan<<<1, 64, 0, stream>>>(ccnt, ccur);
    k_sortgather<<<N_EDGES / 256, 256, 0, stream>>>(eidx, src, dst, etype, erid, att_rc, att_rp,
                                                    src_s, ccur, emC, emC2);
    k_base<<<(NCOMBO * 64 + 255) / 256, 256, 0, stream>>>(type_emb, rid_emb, rc_b, rp_b, baseT);
    k_basew<<<(NLAYER * NCOMBO * 128 + 255) / 256, 256, 0, stream>>>(baseT, W_fij, baseW);
    k_cw<<<(NLAYER * 5 * 128 + 255) / 256, 256, 0, stream>>>(rc_W, rp_W, W_fij, CWf);
    k_wprep<<<(NLAYER * 57344 + 255) / 256, 256, 0, stream>>>(
        W_fij, W_ni, W_nj, W_node, mlp_W1, mlp_W2, WT, W3T, W1T, W2T);
    k_fe<<<N_NODES / 4, 256, 0, stream>>>(feat, fe_W1, fe_b1, fe_W2, fe_b2, h_a, hb_a, out);

    float* hc = h_a;  bf16_t* hbc = hb_a;
    float* hn = h_b;  bf16_t* hbn = hb_b;
    for (int l = 0; l < NLAYER; l++) {
        k_node3<<<NPAD / 32, 256, 0, stream>>>(hbc, W3T + (size_t)l * 384 * 64, b_node + l * 128, s);
        k_edge<<<N_EDGES / 512, 256, 0, stream>>>(s, baseW + (size_t)l * NCOMBO * 128,
                                                  CWf + (size_t)l * 640, attn + l * 128,
                                                  emC, emC2, ev);
        k_soft_agg<<<4096, 256, 0, stream>>>(rowptr, src_s, ev, s, (unsigned*)aggb);
        k_mlp<<<NPAD / 32, 256, 0, stream>>>(aggb, W1T + (size_t)l * 128 * 128, mlp_b1 + l * 128,
                                             W2T + (size_t)l * 64 * 128, mlp_b2 + l * 64,
                                             hc, hn, hbn, out, 32 + 64 * (l + 1));
        float* tf = hc; hc = hn; hn = tf;
        bf16_t* tb = hbc; hbc = hbn; hbn = tb;
    }
    k_colmax<<<512, 384, 0, stream>>>(out, gmax);
    k_bcast<<<512, 384, 0, stream>>>(gmax, out);
}

// Round 8
// 1193.317 us; speedup vs baseline: 1.4143x; 1.4143x over previous
//
#include <hip/hip_runtime.h>
#include <math.h>

// Problem constants (fixed by the reference).
#define N_NODES 50000
#define N_EDGES 640000   // divisible by 32 and 512
#define NLAYER  4
#define NPAD    50016    // N_NODES rounded up to 32
#define NCOMBO  315      // 35 etypes x 9 rids

typedef unsigned short bf16_t;
typedef __attribute__((ext_vector_type(8))) short s16x8;   // 8 bf16 = 4 VGPR (MFMA A/B frag)
typedef __attribute__((ext_vector_type(4))) float f32x4;   // MFMA C/D frag

__device__ __forceinline__ float gelu_f(float x) {
    return 0.5f * x * (1.0f + tanhf(0.7978845608028654f * (x + 0.044715f * x * x * x)));
}

__device__ __forceinline__ bf16_t f2bf(float f) {
    unsigned u = __float_as_uint(f);
    unsigned r = (u + 0x7FFFu + ((u >> 16) & 1u)) >> 16;   // RNE
    return (bf16_t)r;
}
__device__ __forceinline__ float bf2f(bf16_t h) { return __uint_as_float(((unsigned)h) << 16); }
__device__ __forceinline__ float bfl(unsigned x) { return __uint_as_float(x << 16); }
__device__ __forceinline__ float bfh(unsigned x) { return __uint_as_float(x & 0xFFFF0000u); }

// ---------------- CSR build (counting sort by dst) ----------------
__global__ void k_zero32(unsigned* p, int n) {
    int i = blockIdx.x * 256 + threadIdx.x;
    if (i < n) p[i] = 0u;
}

__global__ void k_hist(const int* __restrict__ dst, int* __restrict__ deg) {
    int i = blockIdx.x * 256 + threadIdx.x;
    if (i < N_EDGES) atomicAdd(&deg[dst[i]], 1);
}

__global__ void k_scan1(const int* __restrict__ deg, int* __restrict__ rowptr, int* __restrict__ bsum) {
    __shared__ int sd[1024];
    int gi = blockIdx.x * 1024 + threadIdx.x;
    int v = (gi < N_NODES) ? deg[gi] : 0;
    sd[threadIdx.x] = v;
    __syncthreads();
    for (int off = 1; off < 1024; off <<= 1) {
        int t2 = (threadIdx.x >= (unsigned)off) ? sd[threadIdx.x - off] : 0;
        __syncthreads();
        sd[threadIdx.x] += t2;
        __syncthreads();
    }
    if (gi < N_NODES) rowptr[gi] = sd[threadIdx.x] - v;  // block-local exclusive
    if (threadIdx.x == 1023) bsum[blockIdx.x] = sd[1023];
}

__global__ void k_scan2(const int* __restrict__ bsum, int* __restrict__ boff, int nb) {
    if (threadIdx.x == 0 && blockIdx.x == 0) {
        int run = 0;
        for (int b = 0; b < nb; b++) { boff[b] = run; run += bsum[b]; }
    }
}

// scan3 also seeds the scatter cursor (folds the old k_copy).
__global__ void k_scan3(int* __restrict__ rowptr, const int* __restrict__ boff,
                        int* __restrict__ cursor) {
    int gi = blockIdx.x * 1024 + threadIdx.x;
    if (gi < N_NODES) {
        int v = rowptr[gi] + boff[blockIdx.x];
        rowptr[gi] = v;
        cursor[gi] = v;
    }
    if (gi == 0) rowptr[N_NODES] = N_EDGES;
}

__global__ void k_scatter(const int* __restrict__ dst, int* __restrict__ cursor, int* __restrict__ eidx) {
    int i = blockIdx.x * 256 + threadIdx.x;
    if (i < N_EDGES) {
        int p = atomicAdd(&cursor[dst[i]], 1);
        eidx[p] = i;
    }
}

// Gather per-edge fields into dst-sorted order, compact 24 B/edge (coalesced writes):
// emA[i] = { src, dst, combo = etype*9+erid, rc0|rc1<<16 (bf16) }
// emB[i] = { rp0|rp1<<16 (bf16), rp2 (bf16) }
__global__ void k_sortgather(
    const int* __restrict__ eidx, const int* __restrict__ src, const int* __restrict__ dst,
    const int* __restrict__ etype, const int* __restrict__ erid,
    const float* __restrict__ att_rc, const float* __restrict__ att_rp,
    int* __restrict__ src_s, uint4* __restrict__ emA, uint2* __restrict__ emB)
{
    int i = blockIdx.x * 256 + threadIdx.x;
    if (i < N_EDGES) {
        int e = eidx[i];
        int sv = src[e];
        src_s[i] = sv;
        uint4 a;
        a.x = (unsigned)sv;
        a.y = (unsigned)dst[e];
        a.z = (unsigned)(etype[e] * 9 + erid[e]);
        a.w = (unsigned)f2bf(att_rc[2 * e]) | ((unsigned)f2bf(att_rc[2 * e + 1]) << 16);
        uint2 b;
        b.x = (unsigned)f2bf(att_rp[3 * e]) | ((unsigned)f2bf(att_rp[3 * e + 1]) << 16);
        b.y = (unsigned)f2bf(att_rp[3 * e + 2]);
        emA[i] = a;
        emB[i] = b;
    }
}

// ---------------- (etype,erid)-combo base table: 315 x 64 fp32 ----------
__global__ void k_base(const float* __restrict__ type_emb, const float* __restrict__ rid_emb,
                       const float* __restrict__ rcb, const float* __restrict__ rpb,
                       float* __restrict__ base)
{
    int idx = blockIdx.x * 256 + threadIdx.x;
    if (idx >= NCOMBO * 64) return;
    int c = idx >> 6, k = idx & 63;
    int et = c / 9, er = c % 9;
    base[idx] = type_emb[et * 64 + k] + rid_emb[er * 64 + k] + rcb[k] + rpb[k];
}

// ---------------- rank-factorized edge projection tables (per layer, fp32) ----------
// baseW[l][c][n] = sum_k base[c][k] * Wfij[l][k][n]   (161 KB total, L2-resident)
__global__ void k_basew(const float* __restrict__ base, const float* __restrict__ Wfij,
                        float* __restrict__ baseW)
{
    int idx = blockIdx.x * 256 + threadIdx.x;
    if (idx >= NLAYER * NCOMBO * 128) return;
    int l = idx / (NCOMBO * 128), r = idx % (NCOMBO * 128);
    int c = r >> 7, n = r & 127;
    const float* bp = base + c * 64;
    const float* wp = Wfij + l * 8192 + n;
    float acc = 0.f;
#pragma unroll 8
    for (int k = 0; k < 64; k++) acc = fmaf(bp[k], wp[k * 128], acc);
    baseW[idx] = acc;
}

// CWf[l][j][n] = sum_k w_j[k] * Wfij[l][k][n]
__global__ void k_cw(const float* __restrict__ rcW, const float* __restrict__ rpW,
                     const float* __restrict__ Wfij, float* __restrict__ CWf)
{
    int idx = blockIdx.x * 256 + threadIdx.x;
    if (idx >= NLAYER * 5 * 128) return;
    int l = idx / 640, r = idx % 640;
    int j = r >> 7, n = r & 127;
    const float* cp = (j < 2) ? (rcW + j * 64) : (rpW + (j - 2) * 64);
    const float* wp = Wfij + l * 8192 + n;
    float acc = 0.f;
#pragma unroll 8
    for (int k = 0; k < 64; k++) acc = fmaf(cp[k], wp[k * 128], acc);
    CWf[idx] = acc;
}

// Weight transposes to bf16, k-contiguous rows (MFMA A-operand friendly).
__global__ void k_wprep(const float* __restrict__ Wfij, const float* __restrict__ Wni,
                        const float* __restrict__ Wnj, const float* __restrict__ Wnode,
                        const float* __restrict__ W1, const float* __restrict__ W2,
                        bf16_t* __restrict__ WT, bf16_t* __restrict__ W3T,
                        bf16_t* __restrict__ W1T, bf16_t* __restrict__ W2T)
{
    int idx = blockIdx.x * 256 + threadIdx.x;
    if (idx >= NLAYER * 57344) return;
    int l = idx / 57344, r = idx % 57344;
    if (r < 8192) {
        int n = r >> 6, k = r & 63;
        WT[l * 8192 + r] = f2bf(Wfij[l * 8192 + k * 128 + n]);
    } else if (r < 32768) {
        int q = r - 8192; int c = q >> 6, k = q & 63;
        const float* src = (c < 128) ? Wni : (c < 256) ? Wnj : Wnode;
        W3T[l * 24576 + q] = f2bf(src[l * 8192 + k * 128 + (c & 127)]);
    } else if (r < 49152) {
        int q = r - 32768; int n = q >> 7, k = q & 127;
        W1T[l * 16384 + q] = f2bf(W1[l * 16384 + k * 128 + n]);
    } else {
        int q = r - 49152; int j = q >> 7, k = q & 127;
        W2T[l * 8192 + q] = f2bf(W2[l * 8192 + k * 64 + j]);
    }
}

// ---------------- feature encoder: h0 = gelu(feat@W1+b1)@W2+b2 ----------------
__global__ __launch_bounds__(256) void k_fe(
    const float* __restrict__ feat, const float* __restrict__ W1, const float* __restrict__ b1,
    const float* __restrict__ W2, const float* __restrict__ b2,
    float* __restrict__ h, bf16_t* __restrict__ hb, float* __restrict__ out)
{
    __shared__ float hid[4][64];
    int w = threadIdx.x >> 6, lane = threadIdx.x & 63;
    int n = blockIdx.x * 4 + w;  // N divisible by 4
    float a = b1[lane];
#pragma unroll 8
    for (int k = 0; k < 32; k++) a = fmaf(feat[n * 32 + k], W1[k * 64 + lane], a);
    hid[w][lane] = gelu_f(a);
    __syncthreads();
    float o = b2[lane];
#pragma unroll 8
    for (int k = 0; k < 64; k++) o = fmaf(hid[w][k], W2[k * 64 + lane], o);
    h[n * 64 + lane] = o;
    hb[n * 64 + lane] = f2bf(o);
    out[n * 704 + 32 + lane] = o;
    if (lane < 32) out[n * 704 + lane] = feat[n * 32 + lane];
}

// ---------------- s = h @ [W_ni | W_nj | W_node(+b)] -> [NPAD,384] bf16, MFMA -------------
// Also emits the compact k_edge gather table s_e[NPAD][128]: cols 0..63 = s cols 0..63 (ni),
// cols 64..127 = s cols 128..191 (nj). 12.8 MB working set for k_edge's random gathers.
__global__ __launch_bounds__(256) void k_node3(
    const bf16_t* __restrict__ hb, const bf16_t* __restrict__ W3T,
    const float* __restrict__ bnode, bf16_t* __restrict__ s, bf16_t* __restrict__ s_e)
{
    __shared__ __align__(16) bf16_t hbS[32 * 72];
    const int t = threadIdx.x;
    const int wave = t >> 6, lane = t & 63, l16 = lane & 15, quad = lane >> 4;
    const int n0 = blockIdx.x * 32;
    {   // stage hb tile: 32 rows x 128B
        int r = t >> 3, sg = t & 7;
        *(s16x8*)(hbS + r * 72 + sg * 8) = *(const s16x8*)(hb + (size_t)(n0 + r) * 64 + sg * 8);
    }
    __syncthreads();
    const int ng = wave & 1, ch = wave >> 1;
    const s16x8 B0 = *(const s16x8*)(hbS + (ng * 16 + l16) * 72 + quad * 8);
    const s16x8 B1 = *(const s16x8*)(hbS + (ng * 16 + l16) * 72 + 32 + quad * 8);
    const int node = n0 + ng * 16 + l16;
#pragma unroll
    for (int nt = 0; nt < 12; nt++) {
        int c0 = ch * 192 + nt * 16;
        const s16x8 A0 = *(const s16x8*)(W3T + (size_t)(c0 + l16) * 64 + quad * 8);
        const s16x8 A1 = *(const s16x8*)(W3T + (size_t)(c0 + l16) * 64 + 32 + quad * 8);
        f32x4 acc = {0.f, 0.f, 0.f, 0.f};
        acc = __builtin_amdgcn_mfma_f32_16x16x32_bf16(A0, B0, acc, 0, 0, 0);
        acc = __builtin_amdgcn_mfma_f32_16x16x32_bf16(A1, B1, acc, 0, 0, 0);
        int cb = c0 + quad * 4;
        float4 bv = make_float4(0.f, 0.f, 0.f, 0.f);
        if (cb >= 256) bv = *(const float4*)(bnode + cb - 256);
        ushort4 o;
        o.x = f2bf(acc[0] + bv.x);
        o.y = f2bf(acc[1] + bv.y);
        o.z = f2bf(acc[2] + bv.z);
        o.w = f2bf(acc[3] + bv.w);
        *(ushort4*)(s + (size_t)node * 384 + cb) = o;
        if (cb < 64)
            *(ushort4*)(s_e + (size_t)node * 128 + cb) = o;
        else if (cb >= 128 && cb < 192)
            *(ushort4*)(s_e + (size_t)node * 128 + cb - 64) = o;
    }
}

// ---------------- fused edge kernel: dst-order, 2 edges/thread, compact table, pure VALU -------
// Per-edge math bit-identical to the harness-verified R6 kernel. Differences are purely
// structural: gathers hit the 12.8 MB s_e table (2 aligned 128B rows/edge, dst rows L1-local
// in dst-sorted order), 16 gathers issued up front per thread (2x MLP), evals written as one
// coalesced float4. CWf/attn reads are wave-uniform (scalarized); baseW rows are L2-resident.
__global__ __launch_bounds__(256) void k_edge(
    const bf16_t* __restrict__ s_e, const float* __restrict__ baseW,
    const float* __restrict__ CWf, const float* __restrict__ attn,
    const uint4* __restrict__ emA, const uint2* __restrict__ emB,
    float* __restrict__ evals)
{
    const int t = blockIdx.x * 256 + threadIdx.x;   // grid covers N_EDGES/2 exactly
    const int j = 2 * t;
    const uint4 mA = emA[j], mB = emA[j + 1];
    const uint2 nA = emB[j], nB = emB[j + 1];
    const bf16_t* srA = s_e + (size_t)mA.x * 128;         // sni dims 0..63
    const bf16_t* drA = s_e + (size_t)mA.y * 128 + 64;    // snj dims 0..63
    const bf16_t* srB = s_e + (size_t)mB.x * 128;
    const bf16_t* drB = s_e + (size_t)mB.y * 128 + 64;
    const float* bwA = baseW + (size_t)mA.z * 128;
    const float* bwB = baseW + (size_t)mB.z * 128;
    const float rA0 = bfl(mA.w), rA1 = bfh(mA.w);
    const float rA2 = bfl(nA.x), rA3 = bfh(nA.x), rA4 = bfl(nA.y);
    const float rB0 = bfl(mB.w), rB1 = bfh(mB.w);
    const float rB2 = bfl(nB.x), rB3 = bfh(nB.x), rB4 = bfl(nB.y);

    float eA[2] = {0.f, 0.f};
    float eB[2] = {0.f, 0.f};
#pragma unroll
    for (int c = 0; c < 4; c++) {
        const int d0 = c * 16;
        const uint4 uA0 = *(const uint4*)(srA + d0);
        const uint4 uA1 = *(const uint4*)(srA + d0 + 8);
        const uint4 vA0 = *(const uint4*)(drA + d0);
        const uint4 vA1 = *(const uint4*)(drA + d0 + 8);
        const uint4 uB0 = *(const uint4*)(srB + d0);
        const uint4 uB1 = *(const uint4*)(srB + d0 + 8);
        const uint4 vB0 = *(const uint4*)(drB + d0);
        const uint4 vB1 = *(const uint4*)(drB + d0 + 8);
        float sndA[16], sndB[16];
        sndA[0]  = bfl(uA0.x) + bfl(vA0.x);  sndA[1]  = bfh(uA0.x) + bfh(vA0.x);
        sndA[2]  = bfl(uA0.y) + bfl(vA0.y);  sndA[3]  = bfh(uA0.y) + bfh(vA0.y);
        sndA[4]  = bfl(uA0.z) + bfl(vA0.z);  sndA[5]  = bfh(uA0.z) + bfh(vA0.z);
        sndA[6]  = bfl(uA0.w) + bfl(vA0.w);  sndA[7]  = bfh(uA0.w) + bfh(vA0.w);
        sndA[8]  = bfl(uA1.x) + bfl(vA1.x);  sndA[9]  = bfh(uA1.x) + bfh(vA1.x);
        sndA[10] = bfl(uA1.y) + bfl(vA1.y);  sndA[11] = bfh(uA1.y) + bfh(vA1.y);
        sndA[12] = bfl(uA1.z) + bfl(vA1.z);  sndA[13] = bfh(uA1.z) + bfh(vA1.z);
        sndA[14] = bfl(uA1.w) + bfl(vA1.w);  sndA[15] = bfh(uA1.w) + bfh(vA1.w);
        sndB[0]  = bfl(uB0.x) + bfl(vB0.x);  sndB[1]  = bfh(uB0.x) + bfh(vB0.x);
        sndB[2]  = bfl(uB0.y) + bfl(vB0.y);  sndB[3]  = bfh(uB0.y) + bfh(vB0.y);
        sndB[4]  = bfl(uB0.z) + bfl(vB0.z);  sndB[5]  = bfh(uB0.z) + bfh(vB0.z);
        sndB[6]  = bfl(uB0.w) + bfl(vB0.w);  sndB[7]  = bfh(uB0.w) + bfh(vB0.w);
        sndB[8]  = bfl(uB1.x) + bfl(vB1.x);  sndB[9]  = bfh(uB1.x) + bfh(vB1.x);
        sndB[10] = bfl(uB1.y) + bfl(vB1.y);  sndB[11] = bfh(uB1.y) + bfh(vB1.y);
        sndB[12] = bfl(uB1.z) + bfl(vB1.z);  sndB[13] = bfh(uB1.z) + bfh(vB1.z);
        sndB[14] = bfl(uB1.w) + bfl(vB1.w);  sndB[15] = bfh(uB1.w) + bfh(vB1.w);
#pragma unroll
        for (int h = 0; h < 2; h++) {
#pragma unroll
            for (int q = 0; q < 4; q++) {
                const int n = h * 64 + d0 + q * 4;
                const float4 w0 = *(const float4*)(CWf + n);
                const float4 w1 = *(const float4*)(CWf + 128 + n);
                const float4 w2 = *(const float4*)(CWf + 256 + n);
                const float4 w3 = *(const float4*)(CWf + 384 + n);
                const float4 w4 = *(const float4*)(CWf + 512 + n);
                const float4 at = *(const float4*)(attn + n);
                const float4 bA = *(const float4*)(bwA + n);
                const float4 bB = *(const float4*)(bwB + n);
                float f0 = bA.x, f1 = bA.y, f2 = bA.z, f3 = bA.w;
                f0 = fmaf(rA0, w0.x, f0); f1 = fmaf(rA0, w0.y, f1); f2 = fmaf(rA0, w0.z, f2); f3 = fmaf(rA0, w0.w, f3);
                f0 = fmaf(rA1, w1.x, f0); f1 = fmaf(rA1, w1.y, f1); f2 = fmaf(rA1, w1.z, f2); f3 = fmaf(rA1, w1.w, f3);
                f0 = fmaf(rA2, w2.x, f0); f1 = fmaf(rA2, w2.y, f1); f2 = fmaf(rA2, w2.z, f2); f3 = fmaf(rA2, w2.w, f3);
                f0 = fmaf(rA3, w3.x, f0); f1 = fmaf(rA3, w3.y, f1); f2 = fmaf(rA3, w3.z, f2); f3 = fmaf(rA3, w3.w, f3);
                f0 = fmaf(rA4, w4.x, f0); f1 = fmaf(rA4, w4.y, f1); f2 = fmaf(rA4, w4.z, f2); f3 = fmaf(rA4, w4.w, f3);
                f0 += sndA[q * 4 + 0];
                f1 += sndA[q * 4 + 1];
                f2 += sndA[q * 4 + 2];
                f3 += sndA[q * 4 + 3];
                f0 = (f0 >= 0.f) ? f0 : 0.2f * f0;
                f1 = (f1 >= 0.f) ? f1 : 0.2f * f1;
                f2 = (f2 >= 0.f) ? f2 : 0.2f * f2;
                f3 = (f3 >= 0.f) ? f3 : 0.2f * f3;
                eA[h] = fmaf(f0, at.x, eA[h]);
                eA[h] = fmaf(f1, at.y, eA[h]);
                eA[h] = fmaf(f2, at.z, eA[h]);
                eA[h] = fmaf(f3, at.w, eA[h]);
                float g0 = bB.x, g1 = bB.y, g2 = bB.z, g3 = bB.w;
                g0 = fmaf(rB0, w0.x, g0); g1 = fmaf(rB0, w0.y, g1); g2 = fmaf(rB0, w0.z, g2); g3 = fmaf(rB0, w0.w, g3);
                g0 = fmaf(rB1, w1.x, g0); g1 = fmaf(rB1, w1.y, g1); g2 = fmaf(rB1, w1.z, g2); g3 = fmaf(rB1, w1.w, g3);
                g0 = fmaf(rB2, w2.x, g0); g1 = fmaf(rB2, w2.y, g1); g2 = fmaf(rB2, w2.z, g2); g3 = fmaf(rB2, w2.w, g3);
                g0 = fmaf(rB3, w3.x, g0); g1 = fmaf(rB3, w3.y, g1); g2 = fmaf(rB3, w3.z, g2); g3 = fmaf(rB3, w3.w, g3);
                g0 = fmaf(rB4, w4.x, g0); g1 = fmaf(rB4, w4.y, g1); g2 = fmaf(rB4, w4.z, g2); g3 = fmaf(rB4, w4.w, g3);
                g0 += sndB[q * 4 + 0];
                g1 += sndB[q * 4 + 1];
                g2 += sndB[q * 4 + 2];
                g3 += sndB[q * 4 + 3];
                g0 = (g0 >= 0.f) ? g0 : 0.2f * g0;
                g1 = (g1 >= 0.f) ? g1 : 0.2f * g1;
                g2 = (g2 >= 0.f) ? g2 : 0.2f * g2;
                g3 = (g3 >= 0.f) ? g3 : 0.2f * g3;
                eB[h] = fmaf(g0, at.x, eB[h]);
                eB[h] = fmaf(g1, at.y, eB[h]);
                eB[h] = fmaf(g2, at.z, eB[h]);
                eB[h] = fmaf(g3, at.w, eB[h]);
            }
        }
    }
    float4 o;
    o.x = eA[0]; o.y = eA[1]; o.z = eB[0]; o.w = eB[1];
    *(float4*)(evals + 4 * (size_t)t) = o;   // coalesced: edges j, j+1
}

// ---------------- per-dst softmax + aggregation -> aggb bf16 ----------------
__global__ __launch_bounds__(256) void k_soft_agg(
    const int* __restrict__ rowptr, const int* __restrict__ src_s,
    const float* __restrict__ evals, const bf16_t* __restrict__ s,
    unsigned* __restrict__ aggb)   // [NPAD][64] uints = [NPAD][128] bf16
{
    int lane = threadIdx.x & 63;
    int wid = (blockIdx.x * 256 + threadIdx.x) >> 6;
    int nw = (gridDim.x * 256) >> 6;
    const int hb = (lane >> 4) & 1;                    // head for this lane's dims
    const int esel = lane >> 5;                        // 0: even edge of pair, 1: odd
    const int s32 = (lane & 15) | ((lane >> 5) << 4);  // 0..31 within head-group
    const int dsel = (lane & 31) * 4;                  // 4 bf16 dims per lane
    for (int n = wid; n < N_NODES; n += nw) {
        int r0 = rowptr[n], r1 = rowptr[n + 1];
        if (r0 == r1) {
            if (lane < 32) { uint2 z; z.x = 0u; z.y = 0u; *(uint2*)(aggb + (size_t)n * 64 + lane * 2) = z; }
            continue;
        }
        float mm = -1e30f;
        for (int i = r0 + s32; i < r1; i += 32) mm = fmaxf(mm, evals[2 * i + hb]);
        mm = fmaxf(mm, __shfl_xor(mm, 1));
        mm = fmaxf(mm, __shfl_xor(mm, 2));
        mm = fmaxf(mm, __shfl_xor(mm, 4));
        mm = fmaxf(mm, __shfl_xor(mm, 8));
        mm = fmaxf(mm, __shfl_xor(mm, 32));
        float z = 0.f;
        for (int i = r0 + s32; i < r1; i += 32) z += expf(evals[2 * i + hb] - mm);
        z += __shfl_xor(z, 1);
        z += __shfl_xor(z, 2);
        z += __shfl_xor(z, 4);
        z += __shfl_xor(z, 8);
        z += __shfl_xor(z, 32);
        float rz = 1.f / z;
        float acc0 = 0.f, acc1 = 0.f, acc2 = 0.f, acc3 = 0.f;
        for (int i = r0; i < r1; i += 8) {
            uint2 cc[4]; float ww[4];
#pragma unroll
            for (int p = 0; p < 4; p++) {
                int ej = i + 2 * p + esel;
                bool v = ej < r1;
                int es = v ? ej : r0;
                cc[p] = *(const uint2*)(s + (size_t)src_s[es] * 384 + 256 + dsel);
                ww[p] = v ? expf(evals[2 * ej + hb] - mm) * rz : 0.f;
            }
#pragma unroll
            for (int p = 0; p < 4; p++) {
                acc0 = fmaf(ww[p], bfl(cc[p].x), acc0);
                acc1 = fmaf(ww[p], bfh(cc[p].x), acc1);
                acc2 = fmaf(ww[p], bfl(cc[p].y), acc2);
                acc3 = fmaf(ww[p], bfh(cc[p].y), acc3);
            }
        }
        acc0 += __shfl_xor(acc0, 32);
        acc1 += __shfl_xor(acc1, 32);
        acc2 += __shfl_xor(acc2, 32);
        acc3 += __shfl_xor(acc3, 32);
        if (lane < 32) {
            uint2 o;
            o.x = (unsigned)f2bf(acc0) | ((unsigned)f2bf(acc1) << 16);
            o.y = (unsigned)f2bf(acc2) | ((unsigned)f2bf(acc3) << 16);
            *(uint2*)(aggb + (size_t)n * 64 + lane * 2) = o;
        }
    }
}

// ---------------- node MLP + residual, MFMA: h' = gelu(agg@W1+b1)@W2+b2 + h ----------------
__global__ __launch_bounds__(256) void k_mlp(
    const bf16_t* __restrict__ aggb, const bf16_t* __restrict__ W1T, const float* __restrict__ b1,
    const bf16_t* __restrict__ W2T, const float* __restrict__ b2,
    const float* __restrict__ hin, float* __restrict__ hout, bf16_t* __restrict__ houtb,
    float* __restrict__ out, int col0)
{
    __shared__ __align__(16) bf16_t aggS[32 * 136];
    __shared__ __align__(16) bf16_t hidS[32 * 136];
    const int t = threadIdx.x;
    const int wave = t >> 6, lane = t & 63, l16 = lane & 15, quad = lane >> 4;
    const int n0 = blockIdx.x * 32;
    {   // stage agg tile: 32 rows x 256B (32B per thread)
        int r = t >> 3, sg = t & 7;
        *(s16x8*)(aggS + r * 136 + sg * 16) =
            *(const s16x8*)(aggb + (size_t)(n0 + r) * 128 + sg * 16);
        *(s16x8*)(aggS + r * 136 + sg * 16 + 8) =
            *(const s16x8*)(aggb + (size_t)(n0 + r) * 128 + sg * 16 + 8);
    }
    __syncthreads();
    const int ng = wave & 1, nh = wave >> 1;
    const int node = n0 + ng * 16 + l16;
    {   // GEMM1 + gelu -> hidS
        const bf16_t* brow = aggS + (ng * 16 + l16) * 136 + quad * 8;
        s16x8 B[4];
#pragma unroll
        for (int ks = 0; ks < 4; ks++) B[ks] = *(const s16x8*)(brow + ks * 32);
#pragma unroll
        for (int nt = 0; nt < 4; nt++) {
            int nb = nh * 64 + nt * 16;
            f32x4 acc = {0.f, 0.f, 0.f, 0.f};
#pragma unroll
            for (int ks = 0; ks < 4; ks++) {
                const s16x8 A = *(const s16x8*)(W1T + (size_t)(nb + l16) * 128 + ks * 32 + quad * 8);
                acc = __builtin_amdgcn_mfma_f32_16x16x32_bf16(A, B[ks], acc, 0, 0, 0);
            }
            const float4 bv = *(const float4*)(b1 + nb + quad * 4);
            ushort4 o;
            o.x = f2bf(gelu_f(acc[0] + bv.x));
            o.y = f2bf(gelu_f(acc[1] + bv.y));
            o.z = f2bf(gelu_f(acc[2] + bv.z));
            o.w = f2bf(gelu_f(acc[3] + bv.w));
            *(ushort4*)(hidS + (ng * 16 + l16) * 136 + nb + quad * 4) = o;
        }
    }
    __syncthreads();
    {   // GEMM2 + bias + residual -> hout/houtb/out
        const int jh = wave >> 1;
        const bf16_t* hrow = hidS + (ng * 16 + l16) * 136 + quad * 8;
        s16x8 H[4];
#pragma unroll
        for (int ks = 0; ks < 4; ks++) H[ks] = *(const s16x8*)(hrow + ks * 32);
#pragma unroll
        for (int jt = 0; jt < 2; jt++) {
            int jb = jh * 32 + jt * 16;
            f32x4 acc = {0.f, 0.f, 0.f, 0.f};
#pragma unroll
            for (int ks = 0; ks < 4; ks++) {
                const s16x8 A = *(const s16x8*)(W2T + (size_t)(jb + l16) * 128 + ks * 32 + quad * 8);
                acc = __builtin_amdgcn_mfma_f32_16x16x32_bf16(A, H[ks], acc, 0, 0, 0);
            }
            int j0 = jb + quad * 4;
            const float4 bv = *(const float4*)(b2 + j0);
            const float4 hv = *(const float4*)(hin + (size_t)node * 64 + j0);
            float4 v;
            v.x = acc[0] + bv.x + hv.x;
            v.y = acc[1] + bv.y + hv.y;
            v.z = acc[2] + bv.z + hv.z;
            v.w = acc[3] + bv.w + hv.w;
            *(float4*)(hout + (size_t)node * 64 + j0) = v;
            ushort4 ob;
            ob.x = f2bf(v.x); ob.y = f2bf(v.y); ob.z = f2bf(v.z); ob.w = f2bf(v.w);
            *(ushort4*)(houtb + (size_t)node * 64 + j0) = ob;
            if (node < N_NODES)
                *(float4*)(out + (size_t)node * 704 + col0 + j0) = v;
        }
    }
}

// ---------------- graph max pooling over node_emb cols 0..351 ----------------
__device__ __forceinline__ unsigned fmap(float v) {
    unsigned u = __float_as_uint(v);
    return (u & 0x80000000u) ? ~u : (u | 0x80000000u);
}

__global__ __launch_bounds__(384) void k_colmax(const float* __restrict__ out, unsigned* __restrict__ gmax) {
    int c = threadIdx.x;
    if (c >= 352) return;
    float m = -1e30f;
    for (int n = blockIdx.x; n < N_NODES; n += gridDim.x)
        m = fmaxf(m, out[(size_t)n * 704 + c]);
    atomicMax(gmax + c, fmap(m));
}

__global__ __launch_bounds__(384) void k_bcast(const unsigned* __restrict__ gmax, float* __restrict__ out) {
    int c = threadIdx.x;
    if (c >= 352) return;
    unsigned u = gmax[c];
    u = (u & 0x80000000u) ? (u ^ 0x80000000u) : ~u;
    float v = __uint_as_float(u);
    for (int n = blockIdx.x; n < N_NODES; n += gridDim.x)
        out[(size_t)n * 704 + 352 + c] = v;
}

// ---------------- host launcher ----------------
extern "C" void kernel_launch(void* const* d_in, const int* in_sizes, int n_in,
                              void* d_out, int out_size, void* d_ws, size_t ws_size,
                              hipStream_t stream)
{
    (void)in_sizes; (void)n_in; (void)out_size; (void)ws_size;
    const float* feat     = (const float*)d_in[0];
    const float* att_rc   = (const float*)d_in[1];
    const float* att_rp   = (const float*)d_in[2];
    const float* type_emb = (const float*)d_in[3];
    const float* rid_emb  = (const float*)d_in[4];
    const float* rc_W     = (const float*)d_in[5];
    const float* rc_b     = (const float*)d_in[6];
    const float* rp_W     = (const float*)d_in[7];
    const float* rp_b     = (const float*)d_in[8];
    const float* fe_W1    = (const float*)d_in[9];
    const float* fe_b1    = (const float*)d_in[10];
    const float* fe_W2    = (const float*)d_in[11];
    const float* fe_b2    = (const float*)d_in[12];
    const float* W_ni     = (const float*)d_in[13];
    const float* W_nj     = (const float*)d_in[14];
    const float* W_fij    = (const float*)d_in[15];
    const float* W_node   = (const float*)d_in[16];
    const float* b_node   = (const float*)d_in[17];
    const float* attn     = (const float*)d_in[18];
    const float* mlp_W1   = (const float*)d_in[19];
    const float* mlp_b1   = (const float*)d_in[20];
    const float* mlp_W2   = (const float*)d_in[21];
    const float* mlp_b2   = (const float*)d_in[22];
    const int* src   = (const int*)d_in[23];
    const int* dst   = (const int*)d_in[24];
    const int* etype = (const int*)d_in[25];
    const int* erid  = (const int*)d_in[26];
    float* out = (float*)d_out;

    // Workspace layout (byte cursor, all chunks 16B aligned).
    char* cur = (char*)d_ws;
    auto alloc = [&](size_t bytes) { char* p = cur; cur += (bytes + 15) & ~(size_t)15; return p; };
    float* h_a    = (float*)alloc((size_t)NPAD * 64 * 4);
    float* h_b    = (float*)alloc((size_t)NPAD * 64 * 4);
    bf16_t* hb_a  = (bf16_t*)alloc((size_t)NPAD * 64 * 2);
    bf16_t* hb_b  = (bf16_t*)alloc((size_t)NPAD * 64 * 2);
    bf16_t* s     = (bf16_t*)alloc((size_t)NPAD * 384 * 2);
    bf16_t* s_e   = (bf16_t*)alloc((size_t)NPAD * 128 * 2);
    float* ev     = (float*)alloc((size_t)N_EDGES * 2 * 4);
    bf16_t* aggb  = (bf16_t*)alloc((size_t)NPAD * 128 * 2);
    int* deg     = (int*)alloc((size_t)N_NODES * 4);
    int* rowptr  = (int*)alloc((size_t)(N_NODES + 1) * 4);
    int* cursor  = (int*)alloc((size_t)N_NODES * 4);
    int* eidx    = (int*)alloc((size_t)N_EDGES * 4);
    int* src_s   = (int*)alloc((size_t)N_EDGES * 4);
    uint4* emA   = (uint4*)alloc((size_t)N_EDGES * 16);
    uint2* emB   = (uint2*)alloc((size_t)N_EDGES * 8);
    float* baseT = (float*)alloc((size_t)NCOMBO * 64 * 4);
    float* baseW = (float*)alloc((size_t)NLAYER * NCOMBO * 128 * 4);
    float* CWf   = (float*)alloc((size_t)NLAYER * 5 * 128 * 4);
    bf16_t* WT   = (bf16_t*)alloc((size_t)NLAYER * 128 * 64 * 2);
    bf16_t* W3T  = (bf16_t*)alloc((size_t)NLAYER * 384 * 64 * 2);
    bf16_t* W1T  = (bf16_t*)alloc((size_t)NLAYER * 128 * 128 * 2);
    bf16_t* W2T  = (bf16_t*)alloc((size_t)NLAYER * 64 * 128 * 2);
    int* bsum    = (int*)alloc(64 * 4);
    int* boff    = (int*)alloc(64 * 4);
    unsigned* gmax = (unsigned*)alloc(352 * 4);

    const int NB = (N_NODES + 1023) / 1024;  // 49

    k_zero32<<<(N_NODES + 255) / 256, 256, 0, stream>>>((unsigned*)deg, N_NODES);
    k_zero32<<<2, 256, 0, stream>>>(gmax, 352);
    k_hist<<<N_EDGES / 256, 256, 0, stream>>>(dst, deg);
    k_scan1<<<NB, 1024, 0, stream>>>(deg, rowptr, bsum);
    k_scan2<<<1, 64, 0, stream>>>(bsum, boff, NB);
    k_scan3<<<NB, 1024, 0, stream>>>(rowptr, boff, cursor);
    k_scatter<<<N_EDGES / 256, 256, 0, stream>>>(dst, cursor, eidx);
    k_sortgather<<<N_EDGES / 256, 256, 0, stream>>>(eidx, src, dst, etype, erid, att_rc, att_rp,
                                                    src_s, emA, emB);
    k_base<<<(NCOMBO * 64 + 255) / 256, 256, 0, stream>>>(type_emb, rid_emb, rc_b, rp_b, baseT);
    k_basew<<<(NLAYER * NCOMBO * 128 + 255) / 256, 256, 0, stream>>>(baseT, W_fij, baseW);
    k_cw<<<(NLAYER * 5 * 128 + 255) / 256, 256, 0, stream>>>(rc_W, rp_W, W_fij, CWf);
    k_wprep<<<(NLAYER * 57344 + 255) / 256, 256, 0, stream>>>(
        W_fij, W_ni, W_nj, W_node, mlp_W1, mlp_W2, WT, W3T, W1T, W2T);
    k_fe<<<N_NODES / 4, 256, 0, stream>>>(feat, fe_W1, fe_b1, fe_W2, fe_b2, h_a, hb_a, out);

    float* hc = h_a;  bf16_t* hbc = hb_a;
    float* hn = h_b;  bf16_t* hbn = hb_b;
    for (int l = 0; l < NLAYER; l++) {
        k_node3<<<NPAD / 32, 256, 0, stream>>>(hbc, W3T + (size_t)l * 384 * 64, b_node + l * 128,
                                               s, s_e);
        k_edge<<<N_EDGES / 512, 256, 0, stream>>>(s_e, baseW + (size_t)l * NCOMBO * 128,
                                                  CWf + (size_t)l * 640, attn + l * 128,
                                                  emA, emB, ev);
        k_soft_agg<<<4096, 256, 0, stream>>>(rowptr, src_s, ev, s, (unsigned*)aggb);
        k_mlp<<<NPAD / 32, 256, 0, stream>>>(aggb, W1T + (size_t)l * 128 * 128, mlp_b1 + l * 128,
                                             W2T + (size_t)l * 64 * 128, mlp_b2 + l * 64,
                                             hc, hn, hbn, out, 32 + 64 * (l + 1));
        float* tf = hc; hc = hn; hn = tf;
        bf16_t* tb = hbc; hbc = hbn; hbn = tb;
    }
    k_colmax<<<512, 384, 0, stream>>>(out, gmax);
    k_bcast<<<512, 384, 0, stream>>>(gmax, out);
}

// Round 9
// 1162.401 us; speedup vs baseline: 1.4519x; 1.0266x over previous
//
#include <hip/hip_runtime.h>
#include <math.h>

// Problem constants (fixed by the reference).
#define N_NODES 50000
#define N_EDGES 640000   // divisible by 32 and 512
#define NLAYER  4
#define NPAD    50016    // N_NODES rounded up to 32
#define NCOMBO  315      // 35 etypes x 9 rids

// k_edge geometry: 5000 waves (1250 blocks x 4), 16 chunks/wave, 8 edges/chunk.
#define EDGE_BLOCKS 1250
#define EDGE_WSTRIDE 40000   // 5000 waves * 8 edges

typedef unsigned short bf16_t;
typedef __attribute__((ext_vector_type(8))) short s16x8;   // 8 bf16 = 4 VGPR (MFMA A/B frag)
typedef __attribute__((ext_vector_type(4))) float f32x4;   // MFMA C/D frag

__device__ __forceinline__ float gelu_f(float x) {
    return 0.5f * x * (1.0f + tanhf(0.7978845608028654f * (x + 0.044715f * x * x * x)));
}

__device__ __forceinline__ bf16_t f2bf(float f) {
    unsigned u = __float_as_uint(f);
    unsigned r = (u + 0x7FFFu + ((u >> 16) & 1u)) >> 16;   // RNE
    return (bf16_t)r;
}
__device__ __forceinline__ float bf2f(bf16_t h) { return __uint_as_float(((unsigned)h) << 16); }
__device__ __forceinline__ float bfl(unsigned x) { return __uint_as_float(x << 16); }
__device__ __forceinline__ float bfh(unsigned x) { return __uint_as_float(x & 0xFFFF0000u); }

// ---------------- CSR build (counting sort by dst) ----------------
__global__ void k_zero32(unsigned* p, int n) {
    int i = blockIdx.x * 256 + threadIdx.x;
    if (i < n) p[i] = 0u;
}

__global__ void k_hist(const int* __restrict__ dst, int* __restrict__ deg) {
    int i = blockIdx.x * 256 + threadIdx.x;
    if (i < N_EDGES) atomicAdd(&deg[dst[i]], 1);
}

__global__ void k_scan1(const int* __restrict__ deg, int* __restrict__ rowptr, int* __restrict__ bsum) {
    __shared__ int sd[1024];
    int gi = blockIdx.x * 1024 + threadIdx.x;
    int v = (gi < N_NODES) ? deg[gi] : 0;
    sd[threadIdx.x] = v;
    __syncthreads();
    for (int off = 1; off < 1024; off <<= 1) {
        int t2 = (threadIdx.x >= (unsigned)off) ? sd[threadIdx.x - off] : 0;
        __syncthreads();
        sd[threadIdx.x] += t2;
        __syncthreads();
    }
    if (gi < N_NODES) rowptr[gi] = sd[threadIdx.x] - v;  // block-local exclusive
    if (threadIdx.x == 1023) bsum[blockIdx.x] = sd[1023];
}

__global__ void k_scan2(const int* __restrict__ bsum, int* __restrict__ boff, int nb) {
    if (threadIdx.x == 0 && blockIdx.x == 0) {
        int run = 0;
        for (int b = 0; b < nb; b++) { boff[b] = run; run += bsum[b]; }
    }
}

// scan3 also seeds the scatter cursor (folds the old k_copy).
__global__ void k_scan3(int* __restrict__ rowptr, const int* __restrict__ boff,
                        int* __restrict__ cursor) {
    int gi = blockIdx.x * 1024 + threadIdx.x;
    if (gi < N_NODES) {
        int v = rowptr[gi] + boff[blockIdx.x];
        rowptr[gi] = v;
        cursor[gi] = v;
    }
    if (gi == 0) rowptr[N_NODES] = N_EDGES;
}

__global__ void k_scatter(const int* __restrict__ dst, int* __restrict__ cursor, int* __restrict__ eidx) {
    int i = blockIdx.x * 256 + threadIdx.x;
    if (i < N_EDGES) {
        int p = atomicAdd(&cursor[dst[i]], 1);
        eidx[p] = i;
    }
}

// Gather per-edge fields into dst-sorted order, compact 24 B/edge (coalesced writes):
// emA[i] = { src, dst, combo = etype*9+erid, rc0|rc1<<16 (bf16) }
// emB[i] = { rp0|rp1<<16 (bf16), rp2 (bf16) }
__global__ void k_sortgather(
    const int* __restrict__ eidx, const int* __restrict__ src, const int* __restrict__ dst,
    const int* __restrict__ etype, const int* __restrict__ erid,
    const float* __restrict__ att_rc, const float* __restrict__ att_rp,
    int* __restrict__ src_s, uint4* __restrict__ emA, uint2* __restrict__ emB)
{
    int i = blockIdx.x * 256 + threadIdx.x;
    if (i < N_EDGES) {
        int e = eidx[i];
        int sv = src[e];
        src_s[i] = sv;
        uint4 a;
        a.x = (unsigned)sv;
        a.y = (unsigned)dst[e];
        a.z = (unsigned)(etype[e] * 9 + erid[e]);
        a.w = (unsigned)f2bf(att_rc[2 * e]) | ((unsigned)f2bf(att_rc[2 * e + 1]) << 16);
        uint2 b;
        b.x = (unsigned)f2bf(att_rp[3 * e]) | ((unsigned)f2bf(att_rp[3 * e + 1]) << 16);
        b.y = (unsigned)f2bf(att_rp[3 * e + 2]);
        emA[i] = a;
        emB[i] = b;
    }
}

// ---------------- (etype,erid)-combo base table: 315 x 64 fp32 ----------
__global__ void k_base(const float* __restrict__ type_emb, const float* __restrict__ rid_emb,
                       const float* __restrict__ rcb, const float* __restrict__ rpb,
                       float* __restrict__ base)
{
    int idx = blockIdx.x * 256 + threadIdx.x;
    if (idx >= NCOMBO * 64) return;
    int c = idx >> 6, k = idx & 63;
    int et = c / 9, er = c % 9;
    base[idx] = type_emb[et * 64 + k] + rid_emb[er * 64 + k] + rcb[k] + rpb[k];
}

// ---------------- rank-factorized edge projection tables (per layer, fp32) ----------
// baseW[l][c][n] = sum_k base[c][k] * Wfij[l][k][n]   (161 KB total, L2-resident)
__global__ void k_basew(const float* __restrict__ base, const float* __restrict__ Wfij,
                        float* __restrict__ baseW)
{
    int idx = blockIdx.x * 256 + threadIdx.x;
    if (idx >= NLAYER * NCOMBO * 128) return;
    int l = idx / (NCOMBO * 128), r = idx % (NCOMBO * 128);
    int c = r >> 7, n = r & 127;
    const float* bp = base + c * 64;
    const float* wp = Wfij + l * 8192 + n;
    float acc = 0.f;
#pragma unroll 8
    for (int k = 0; k < 64; k++) acc = fmaf(bp[k], wp[k * 128], acc);
    baseW[idx] = acc;
}

// CWf[l][j][n] = sum_k w_j[k] * Wfij[l][k][n]
__global__ void k_cw(const float* __restrict__ rcW, const float* __restrict__ rpW,
                     const float* __restrict__ Wfij, float* __restrict__ CWf)
{
    int idx = blockIdx.x * 256 + threadIdx.x;
    if (idx >= NLAYER * 5 * 128) return;
    int l = idx / 640, r = idx % 640;
    int j = r >> 7, n = r & 127;
    const float* cp = (j < 2) ? (rcW + j * 64) : (rpW + (j - 2) * 64);
    const float* wp = Wfij + l * 8192 + n;
    float acc = 0.f;
#pragma unroll 8
    for (int k = 0; k < 64; k++) acc = fmaf(cp[k], wp[k * 128], acc);
    CWf[idx] = acc;
}

// Weight transposes to bf16, k-contiguous rows (MFMA A-operand friendly).
__global__ void k_wprep(const float* __restrict__ Wfij, const float* __restrict__ Wni,
                        const float* __restrict__ Wnj, const float* __restrict__ Wnode,
                        const float* __restrict__ W1, const float* __restrict__ W2,
                        bf16_t* __restrict__ WT, bf16_t* __restrict__ W3T,
                        bf16_t* __restrict__ W1T, bf16_t* __restrict__ W2T)
{
    int idx = blockIdx.x * 256 + threadIdx.x;
    if (idx >= NLAYER * 57344) return;
    int l = idx / 57344, r = idx % 57344;
    if (r < 8192) {
        int n = r >> 6, k = r & 63;
        WT[l * 8192 + r] = f2bf(Wfij[l * 8192 + k * 128 + n]);
    } else if (r < 32768) {
        int q = r - 8192; int c = q >> 6, k = q & 63;
        const float* src = (c < 128) ? Wni : (c < 256) ? Wnj : Wnode;
        W3T[l * 24576 + q] = f2bf(src[l * 8192 + k * 128 + (c & 127)]);
    } else if (r < 49152) {
        int q = r - 32768; int n = q >> 7, k = q & 127;
        W1T[l * 16384 + q] = f2bf(W1[l * 16384 + k * 128 + n]);
    } else {
        int q = r - 49152; int j = q >> 7, k = q & 127;
        W2T[l * 8192 + q] = f2bf(W2[l * 8192 + k * 64 + j]);
    }
}

// ---------------- feature encoder: h0 = gelu(feat@W1+b1)@W2+b2 ----------------
__global__ __launch_bounds__(256) void k_fe(
    const float* __restrict__ feat, const float* __restrict__ W1, const float* __restrict__ b1,
    const float* __restrict__ W2, const float* __restrict__ b2,
    float* __restrict__ h, bf16_t* __restrict__ hb, float* __restrict__ out)
{
    __shared__ float hid[4][64];
    int w = threadIdx.x >> 6, lane = threadIdx.x & 63;
    int n = blockIdx.x * 4 + w;  // N divisible by 4
    float a = b1[lane];
#pragma unroll 8
    for (int k = 0; k < 32; k++) a = fmaf(feat[n * 32 + k], W1[k * 64 + lane], a);
    hid[w][lane] = gelu_f(a);
    __syncthreads();
    float o = b2[lane];
#pragma unroll 8
    for (int k = 0; k < 64; k++) o = fmaf(hid[w][k], W2[k * 64 + lane], o);
    h[n * 64 + lane] = o;
    hb[n * 64 + lane] = f2bf(o);
    out[n * 704 + 32 + lane] = o;
    if (lane < 32) out[n * 704 + lane] = feat[n * 32 + lane];
}

// ---------------- s = h @ [W_ni | W_nj | W_node(+b)] -> [NPAD,384] bf16, MFMA ----------------
__global__ __launch_bounds__(256) void k_node3(
    const bf16_t* __restrict__ hb, const bf16_t* __restrict__ W3T,
    const float* __restrict__ bnode, bf16_t* __restrict__ s)
{
    __shared__ __align__(16) bf16_t hbS[32 * 72];
    const int t = threadIdx.x;
    const int wave = t >> 6, lane = t & 63, l16 = lane & 15, quad = lane >> 4;
    const int n0 = blockIdx.x * 32;
    {   // stage hb tile: 32 rows x 128B
        int r = t >> 3, sg = t & 7;
        *(s16x8*)(hbS + r * 72 + sg * 8) = *(const s16x8*)(hb + (size_t)(n0 + r) * 64 + sg * 8);
    }
    __syncthreads();
    const int ng = wave & 1, ch = wave >> 1;
    const s16x8 B0 = *(const s16x8*)(hbS + (ng * 16 + l16) * 72 + quad * 8);
    const s16x8 B1 = *(const s16x8*)(hbS + (ng * 16 + l16) * 72 + 32 + quad * 8);
    const int node = n0 + ng * 16 + l16;
#pragma unroll
    for (int nt = 0; nt < 12; nt++) {
        int c0 = ch * 192 + nt * 16;
        const s16x8 A0 = *(const s16x8*)(W3T + (size_t)(c0 + l16) * 64 + quad * 8);
        const s16x8 A1 = *(const s16x8*)(W3T + (size_t)(c0 + l16) * 64 + 32 + quad * 8);
        f32x4 acc = {0.f, 0.f, 0.f, 0.f};
        acc = __builtin_amdgcn_mfma_f32_16x16x32_bf16(A0, B0, acc, 0, 0, 0);
        acc = __builtin_amdgcn_mfma_f32_16x16x32_bf16(A1, B1, acc, 0, 0, 0);
        int cb = c0 + quad * 4;
        float4 bv = make_float4(0.f, 0.f, 0.f, 0.f);
        if (cb >= 256) bv = *(const float4*)(bnode + cb - 256);
        ushort4 o;
        o.x = f2bf(acc[0] + bv.x);
        o.y = f2bf(acc[1] + bv.y);
        o.z = f2bf(acc[2] + bv.z);
        o.w = f2bf(acc[3] + bv.w);
        *(ushort4*)(s + (size_t)node * 384 + cb) = o;
    }
}

// ---------------- fused edge kernel: 8 lanes/edge, dims-across-lanes, pure VALU ----------------
// Lane (eslot = lane&7, q = lane>>3): edge i = chunk*8+eslot, dims n = q*16..q*16+15, head = q>>2.
// All per-edge loads (baseW 4x16B, sni 2x16B, snj 2x16B) issue at iteration top; next chunk's
// meta prefetched 1-deep; CWf/attn loads are loop-invariant (LICM -> once per kernel).
// Per-dim fp32 chain (bw -> 5 fma -> +snd -> leaky -> attn fma) is bit-identical to the
// harness-verified R8 kernel, including the dims-0..63 snd pairing for BOTH heads; only the
// reduction association changes (per-lane 16-dim chain + shfl tree vs sequential).
__global__ __launch_bounds__(256) void k_edge(
    const bf16_t* __restrict__ s, const float* __restrict__ baseW,
    const float* __restrict__ CWf, const float* __restrict__ attn,
    const uint4* __restrict__ emA, const uint2* __restrict__ emB,
    float* __restrict__ evals)
{
    const int lane = (int)threadIdx.x & 63;
    const int eslot = lane & 7;
    const int q = lane >> 3;
    const int dq = (q & 3) * 32;          // byte offset into the 128B sni/snj block
    const int nq = q * 16;                // first output dim owned by this lane
    const int w = ((int)blockIdx.x * 256 + (int)threadIdx.x) >> 6;   // wave id 0..4999

    int i = w * 8 + eslot;
    uint4 ma = emA[i];
    uint2 mb = emB[i];
#pragma unroll 1
    for (int t = 0; t < 16; t++) {
        const int iCur = i;
        // ---- issue all gathers for the current edge up front ----
        const unsigned char* sr = (const unsigned char*)(s + (size_t)ma.x * 384);         // ni cols 0..63
        const unsigned char* dr = (const unsigned char*)(s + (size_t)ma.y * 384 + 128);   // nj cols 128..191
        const uint4 u0 = *(const uint4*)(sr + dq);
        const uint4 u1 = *(const uint4*)(sr + dq + 16);
        const uint4 v0 = *(const uint4*)(dr + dq);
        const uint4 v1 = *(const uint4*)(dr + dq + 16);
        const float* bw = baseW + (size_t)ma.z * 128 + nq;
        const float4 b0 = *(const float4*)(bw + 0);
        const float4 b1 = *(const float4*)(bw + 4);
        const float4 b2 = *(const float4*)(bw + 8);
        const float4 b3 = *(const float4*)(bw + 12);
        const float r0 = bfl(ma.w), r1 = bfh(ma.w);
        const float r2 = bfl(mb.x), r3 = bfh(mb.x), r4 = bfl(mb.y);
        // ---- prefetch next chunk's meta (1-deep pipeline) ----
        i += EDGE_WSTRIDE;
        if (t < 15) { ma = emA[i]; mb = emB[i]; }

        float p = 0.f;
        auto chunk = [&](int k4, unsigned ua, unsigned ub, unsigned va, unsigned vb,
                         const float4& bb) {
            const int n4 = nq + k4 * 4;
            const float4 c0 = *(const float4*)(CWf + n4);          // loop-invariant loads
            const float4 c1 = *(const float4*)(CWf + 128 + n4);
            const float4 c2 = *(const float4*)(CWf + 256 + n4);
            const float4 c3 = *(const float4*)(CWf + 384 + n4);
            const float4 c4 = *(const float4*)(CWf + 512 + n4);
            const float4 at = *(const float4*)(attn + n4);
            float f0 = bb.x, f1 = bb.y, f2 = bb.z, f3 = bb.w;
            f0 = fmaf(r0, c0.x, f0); f1 = fmaf(r0, c0.y, f1); f2 = fmaf(r0, c0.z, f2); f3 = fmaf(r0, c0.w, f3);
            f0 = fmaf(r1, c1.x, f0); f1 = fmaf(r1, c1.y, f1); f2 = fmaf(r1, c1.z, f2); f3 = fmaf(r1, c1.w, f3);
            f0 = fmaf(r2, c2.x, f0); f1 = fmaf(r2, c2.y, f1); f2 = fmaf(r2, c2.z, f2); f3 = fmaf(r2, c2.w, f3);
            f0 = fmaf(r3, c3.x, f0); f1 = fmaf(r3, c3.y, f1); f2 = fmaf(r3, c3.z, f2); f3 = fmaf(r3, c3.w, f3);
            f0 = fmaf(r4, c4.x, f0); f1 = fmaf(r4, c4.y, f1); f2 = fmaf(r4, c4.z, f2); f3 = fmaf(r4, c4.w, f3);
            f0 += bfl(ua) + bfl(va);
            f1 += bfh(ua) + bfh(va);
            f2 += bfl(ub) + bfl(vb);
            f3 += bfh(ub) + bfh(vb);
            f0 = (f0 >= 0.f) ? f0 : 0.2f * f0;
            f1 = (f1 >= 0.f) ? f1 : 0.2f * f1;
            f2 = (f2 >= 0.f) ? f2 : 0.2f * f2;
            f3 = (f3 >= 0.f) ? f3 : 0.2f * f3;
            p = fmaf(f0, at.x, p);
            p = fmaf(f1, at.y, p);
            p = fmaf(f2, at.z, p);
            p = fmaf(f3, at.w, p);
        };
        chunk(0, u0.x, u0.y, v0.x, v0.y, b0);
        chunk(1, u0.z, u0.w, v0.z, v0.w, b1);
        chunk(2, u1.x, u1.y, v1.x, v1.y, b2);
        chunk(3, u1.z, u1.w, v1.z, v1.w, b3);

        // reduce 8 q-lanes -> per-head sums (q0-3: head0, q4-7: head1), pair via xor(32)
        p += __shfl_xor(p, 8);
        p += __shfl_xor(p, 16);
        const float po = __shfl_xor(p, 32);
        if (q == 0) {
            float2 o;
            o.x = p;       // head 0
            o.y = po;      // head 1
            *(float2*)(evals + 2 * (size_t)iCur) = o;   // lanes 0..7: 64B coalesced
        }
    }
}

// ---------------- per-dst softmax + aggregation -> aggb bf16 ----------------
__global__ __launch_bounds__(256) void k_soft_agg(
    const int* __restrict__ rowptr, const int* __restrict__ src_s,
    const float* __restrict__ evals, const bf16_t* __restrict__ s,
    unsigned* __restrict__ aggb)   // [NPAD][64] uints = [NPAD][128] bf16
{
    int lane = threadIdx.x & 63;
    int wid = (blockIdx.x * 256 + threadIdx.x) >> 6;
    int nw = (gridDim.x * 256) >> 6;
    const int hb = (lane >> 4) & 1;                    // head for this lane's dims
    const int esel = lane >> 5;                        // 0: even edge of pair, 1: odd
    const int s32 = (lane & 15) | ((lane >> 5) << 4);  // 0..31 within head-group
    const int dsel = (lane & 31) * 4;                  // 4 bf16 dims per lane
    for (int n = wid; n < N_NODES; n += nw) {
        int r0 = rowptr[n], r1 = rowptr[n + 1];
        if (r0 == r1) {
            if (lane < 32) { uint2 z; z.x = 0u; z.y = 0u; *(uint2*)(aggb + (size_t)n * 64 + lane * 2) = z; }
            continue;
        }
        float mm = -1e30f;
        for (int i = r0 + s32; i < r1; i += 32) mm = fmaxf(mm, evals[2 * i + hb]);
        mm = fmaxf(mm, __shfl_xor(mm, 1));
        mm = fmaxf(mm, __shfl_xor(mm, 2));
        mm = fmaxf(mm, __shfl_xor(mm, 4));
        mm = fmaxf(mm, __shfl_xor(mm, 8));
        mm = fmaxf(mm, __shfl_xor(mm, 32));
        float z = 0.f;
        for (int i = r0 + s32; i < r1; i += 32) z += expf(evals[2 * i + hb] - mm);
        z += __shfl_xor(z, 1);
        z += __shfl_xor(z, 2);
        z += __shfl_xor(z, 4);
        z += __shfl_xor(z, 8);
        z += __shfl_xor(z, 32);
        float rz = 1.f / z;
        float acc0 = 0.f, acc1 = 0.f, acc2 = 0.f, acc3 = 0.f;
        for (int i = r0; i < r1; i += 8) {
            uint2 cc[4]; float ww[4];
#pragma unroll
            for (int p = 0; p < 4; p++) {
                int ej = i + 2 * p + esel;
                bool v = ej < r1;
                int es = v ? ej : r0;
                cc[p] = *(const uint2*)(s + (size_t)src_s[es] * 384 + 256 + dsel);
                ww[p] = v ? expf(evals[2 * ej + hb] - mm) * rz : 0.f;
            }
#pragma unroll
            for (int p = 0; p < 4; p++) {
                acc0 = fmaf(ww[p], bfl(cc[p].x), acc0);
                acc1 = fmaf(ww[p], bfh(cc[p].x), acc1);
                acc2 = fmaf(ww[p], bfl(cc[p].y), acc2);
                acc3 = fmaf(ww[p], bfh(cc[p].y), acc3);
            }
        }
        acc0 += __shfl_xor(acc0, 32);
        acc1 += __shfl_xor(acc1, 32);
        acc2 += __shfl_xor(acc2, 32);
        acc3 += __shfl_xor(acc3, 32);
        if (lane < 32) {
            uint2 o;
            o.x = (unsigned)f2bf(acc0) | ((unsigned)f2bf(acc1) << 16);
            o.y = (unsigned)f2bf(acc2) | ((unsigned)f2bf(acc3) << 16);
            *(uint2*)(aggb + (size_t)n * 64 + lane * 2) = o;
        }
    }
}

// ---------------- node MLP + residual, MFMA: h' = gelu(agg@W1+b1)@W2+b2 + h ----------------
__global__ __launch_bounds__(256) void k_mlp(
    const bf16_t* __restrict__ aggb, const bf16_t* __restrict__ W1T, const float* __restrict__ b1,
    const bf16_t* __restrict__ W2T, const float* __restrict__ b2,
    const float* __restrict__ hin, float* __restrict__ hout, bf16_t* __restrict__ houtb,
    float* __restrict__ out, int col0)
{
    __shared__ __align__(16) bf16_t aggS[32 * 136];
    __shared__ __align__(16) bf16_t hidS[32 * 136];
    const int t = threadIdx.x;
    const int wave = t >> 6, lane = t & 63, l16 = lane & 15, quad = lane >> 4;
    const int n0 = blockIdx.x * 32;
    {   // stage agg tile: 32 rows x 256B (32B per thread)
        int r = t >> 3, sg = t & 7;
        *(s16x8*)(aggS + r * 136 + sg * 16) =
            *(const s16x8*)(aggb + (size_t)(n0 + r) * 128 + sg * 16);
        *(s16x8*)(aggS + r * 136 + sg * 16 + 8) =
            *(const s16x8*)(aggb + (size_t)(n0 + r) * 128 + sg * 16 + 8);
    }
    __syncthreads();
    const int ng = wave & 1, nh = wave >> 1;
    const int node = n0 + ng * 16 + l16;
    {   // GEMM1 + gelu -> hidS
        const bf16_t* brow = aggS + (ng * 16 + l16) * 136 + quad * 8;
        s16x8 B[4];
#pragma unroll
        for (int ks = 0; ks < 4; ks++) B[ks] = *(const s16x8*)(brow + ks * 32);
#pragma unroll
        for (int nt = 0; nt < 4; nt++) {
            int nb = nh * 64 + nt * 16;
            f32x4 acc = {0.f, 0.f, 0.f, 0.f};
#pragma unroll
            for (int ks = 0; ks < 4; ks++) {
                const s16x8 A = *(const s16x8*)(W1T + (size_t)(nb + l16) * 128 + ks * 32 + quad * 8);
                acc = __builtin_amdgcn_mfma_f32_16x16x32_bf16(A, B[ks], acc, 0, 0, 0);
            }
            const float4 bv = *(const float4*)(b1 + nb + quad * 4);
            ushort4 o;
            o.x = f2bf(gelu_f(acc[0] + bv.x));
            o.y = f2bf(gelu_f(acc[1] + bv.y));
            o.z = f2bf(gelu_f(acc[2] + bv.z));
            o.w = f2bf(gelu_f(acc[3] + bv.w));
            *(ushort4*)(hidS + (ng * 16 + l16) * 136 + nb + quad * 4) = o;
        }
    }
    __syncthreads();
    {   // GEMM2 + bias + residual -> hout/houtb/out
        const int jh = wave >> 1;
        const bf16_t* hrow = hidS + (ng * 16 + l16) * 136 + quad * 8;
        s16x8 H[4];
#pragma unroll
        for (int ks = 0; ks < 4; ks++) H[ks] = *(const s16x8*)(hrow + ks * 32);
#pragma unroll
        for (int jt = 0; jt < 2; jt++) {
            int jb = jh * 32 + jt * 16;
            f32x4 acc = {0.f, 0.f, 0.f, 0.f};
#pragma unroll
            for (int ks = 0; ks < 4; ks++) {
                const s16x8 A = *(const s16x8*)(W2T + (size_t)(jb + l16) * 128 + ks * 32 + quad * 8);
                acc = __builtin_amdgcn_mfma_f32_16x16x32_bf16(A, H[ks], acc, 0, 0, 0);
            }
            int j0 = jb + quad * 4;
            const float4 bv = *(const float4*)(b2 + j0);
            const float4 hv = *(const float4*)(hin + (size_t)node * 64 + j0);
            float4 v;
            v.x = acc[0] + bv.x + hv.x;
            v.y = acc[1] + bv.y + hv.y;
            v.z = acc[2] + bv.z + hv.z;
            v.w = acc[3] + bv.w + hv.w;
            *(float4*)(hout + (size_t)node * 64 + j0) = v;
            ushort4 ob;
            ob.x = f2bf(v.x); ob.y = f2bf(v.y); ob.z = f2bf(v.z); ob.w = f2bf(v.w);
            *(ushort4*)(houtb + (size_t)node * 64 + j0) = ob;
            if (node < N_NODES)
                *(float4*)(out + (size_t)node * 704 + col0 + j0) = v;
        }
    }
}

// ---------------- graph max pooling over node_emb cols 0..351 ----------------
__device__ __forceinline__ unsigned fmap(float v) {
    unsigned u = __float_as_uint(v);
    return (u & 0x80000000u) ? ~u : (u | 0x80000000u);
}

__global__ __launch_bounds__(384) void k_colmax(const float* __restrict__ out, unsigned* __restrict__ gmax) {
    int c = threadIdx.x;
    if (c >= 352) return;
    float m = -1e30f;
    for (int n = blockIdx.x; n < N_NODES; n += gridDim.x)
        m = fmaxf(m, out[(size_t)n * 704 + c]);
    atomicMax(gmax + c, fmap(m));
}

__global__ __launch_bounds__(384) void k_bcast(const unsigned* __restrict__ gmax, float* __restrict__ out) {
    int c = threadIdx.x;
    if (c >= 352) return;
    unsigned u = gmax[c];
    u = (u & 0x80000000u) ? (u ^ 0x80000000u) : ~u;
    float v = __uint_as_float(u);
    for (int n = blockIdx.x; n < N_NODES; n += gridDim.x)
        out[(size_t)n * 704 + 352 + c] = v;
}

// ---------------- host launcher ----------------
extern "C" void kernel_launch(void* const* d_in, const int* in_sizes, int n_in,
                              void* d_out, int out_size, void* d_ws, size_t ws_size,
                              hipStream_t stream)
{
    (void)in_sizes; (void)n_in; (void)out_size; (void)ws_size;
    const float* feat     = (const float*)d_in[0];
    const float* att_rc   = (const float*)d_in[1];
    const float* att_rp   = (const float*)d_in[2];
    const float* type_emb = (const float*)d_in[3];
    const float* rid_emb  = (const float*)d_in[4];
    const float* rc_W     = (const float*)d_in[5];
    const float* rc_b     = (const float*)d_in[6];
    const float* rp_W     = (const float*)d_in[7];
    const float* rp_b     = (const float*)d_in[8];
    const float* fe_W1    = (const float*)d_in[9];
    const float* fe_b1    = (const float*)d_in[10];
    const float* fe_W2    = (const float*)d_in[11];
    const float* fe_b2    = (const float*)d_in[12];
    const float* W_ni     = (const float*)d_in[13];
    const float* W_nj     = (const float*)d_in[14];
    const float* W_fij    = (const float*)d_in[15];
    const float* W_node   = (const float*)d_in[16];
    const float* b_node   = (const float*)d_in[17];
    const float* attn     = (const float*)d_in[18];
    const float* mlp_W1   = (const float*)d_in[19];
    const float* mlp_b1   = (const float*)d_in[20];
    const float* mlp_W2   = (const float*)d_in[21];
    const float* mlp_b2   = (const float*)d_in[22];
    const int* src   = (const int*)d_in[23];
    const int* dst   = (const int*)d_in[24];
    const int* etype = (const int*)d_in[25];
    const int* erid  = (const int*)d_in[26];
    float* out = (float*)d_out;

    // Workspace layout (byte cursor, all chunks 16B aligned).
    char* cur = (char*)d_ws;
    auto alloc = [&](size_t bytes) { char* p = cur; cur += (bytes + 15) & ~(size_t)15; return p; };
    float* h_a    = (float*)alloc((size_t)NPAD * 64 * 4);
    float* h_b    = (float*)alloc((size_t)NPAD * 64 * 4);
    bf16_t* hb_a  = (bf16_t*)alloc((size_t)NPAD * 64 * 2);
    bf16_t* hb_b  = (bf16_t*)alloc((size_t)NPAD * 64 * 2);
    bf16_t* s     = (bf16_t*)alloc((size_t)NPAD * 384 * 2);
    float* ev     = (float*)alloc((size_t)N_EDGES * 2 * 4);
    bf16_t* aggb  = (bf16_t*)alloc((size_t)NPAD * 128 * 2);
    int* deg     = (int*)alloc((size_t)N_NODES * 4);
    int* rowptr  = (int*)alloc((size_t)(N_NODES + 1) * 4);
    int* cursor  = (int*)alloc((size_t)N_NODES * 4);
    int* eidx    = (int*)alloc((size_t)N_EDGES * 4);
    int* src_s   = (int*)alloc((size_t)N_EDGES * 4);
    uint4* emA   = (uint4*)alloc((size_t)N_EDGES * 16);
    uint2* emB   = (uint2*)alloc((size_t)N_EDGES * 8);
    float* baseT = (float*)alloc((size_t)NCOMBO * 64 * 4);
    float* baseW = (float*)alloc((size_t)NLAYER * NCOMBO * 128 * 4);
    float* CWf   = (float*)alloc((size_t)NLAYER * 5 * 128 * 4);
    bf16_t* WT   = (bf16_t*)alloc((size_t)NLAYER * 128 * 64 * 2);
    bf16_t* W3T  = (bf16_t*)alloc((size_t)NLAYER * 384 * 64 * 2);
    bf16_t* W1T  = (bf16_t*)alloc((size_t)NLAYER * 128 * 128 * 2);
    bf16_t* W2T  = (bf16_t*)alloc((size_t)NLAYER * 64 * 128 * 2);
    int* bsum    = (int*)alloc(64 * 4);
    int* boff    = (int*)alloc(64 * 4);
    unsigned* gmax = (unsigned*)alloc(352 * 4);

    const int NB = (N_NODES + 1023) / 1024;  // 49

    k_zero32<<<(N_NODES + 255) / 256, 256, 0, stream>>>((unsigned*)deg, N_NODES);
    k_zero32<<<2, 256, 0, stream>>>(gmax, 352);
    k_hist<<<N_EDGES / 256, 256, 0, stream>>>(dst, deg);
    k_scan1<<<NB, 1024, 0, stream>>>(deg, rowptr, bsum);
    k_scan2<<<1, 64, 0, stream>>>(bsum, boff, NB);
    k_scan3<<<NB, 1024, 0, stream>>>(rowptr, boff, cursor);
    k_scatter<<<N_EDGES / 256, 256, 0, stream>>>(dst, cursor, eidx);
    k_sortgather<<<N_EDGES / 256, 256, 0, stream>>>(eidx, src, dst, etype, erid, att_rc, att_rp,
                                                    src_s, emA, emB);
    k_base<<<(NCOMBO * 64 + 255) / 256, 256, 0, stream>>>(type_emb, rid_emb, rc_b, rp_b, baseT);
    k_basew<<<(NLAYER * NCOMBO * 128 + 255) / 256, 256, 0, stream>>>(baseT, W_fij, baseW);
    k_cw<<<(NLAYER * 5 * 128 + 255) / 256, 256, 0, stream>>>(rc_W, rp_W, W_fij, CWf);
    k_wprep<<<(NLAYER * 57344 + 255) / 256, 256, 0, stream>>>(
        W_fij, W_ni, W_nj, W_node, mlp_W1, mlp_W2, WT, W3T, W1T, W2T);
    k_fe<<<N_NODES / 4, 256, 0, stream>>>(feat, fe_W1, fe_b1, fe_W2, fe_b2, h_a, hb_a, out);

    float* hc = h_a;  bf16_t* hbc = hb_a;
    float* hn = h_b;  bf16_t* hbn = hb_b;
    for (int l = 0; l < NLAYER; l++) {
        k_node3<<<NPAD / 32, 256, 0, stream>>>(hbc, W3T + (size_t)l * 384 * 64, b_node + l * 128, s);
        k_edge<<<EDGE_BLOCKS, 256, 0, stream>>>(s, baseW + (size_t)l * NCOMBO * 128,
                                                CWf + (size_t)l * 640, attn + l * 128,
                                                emA, emB, ev);
        k_soft_agg<<<4096, 256, 0, stream>>>(rowptr, src_s, ev, s, (unsigned*)aggb);
        k_mlp<<<NPAD / 32, 256, 0, stream>>>(aggb, W1T + (size_t)l * 128 * 128, mlp_b1 + l * 128,
                                             W2T + (size_t)l * 64 * 128, mlp_b2 + l * 64,
                                             hc, hn, hbn, out, 32 + 64 * (l + 1));
        float* tf = hc; hc = hn; hn = tf;
        bf16_t* tb = hbc; hbc = hbn; hbn = tb;
    }
    k_colmax<<<512, 384, 0, stream>>>(out, gmax);
    k_bcast<<<512, 384, 0, stream>>>(gmax, out);
}